// Round 5
// baseline (709.584 us; speedup 1.0000x reference)
//
#include <hip/hip_runtime.h>
#include <math.h>

#define T_LEN 8192
#define KK 64
#define DD 128
#define RS 132
#define GP 68
#define NB 256

typedef __bf16  bf16x4 __attribute__((ext_vector_type(4)));
typedef __bf16  bf16x8 __attribute__((ext_vector_type(8)));
typedef float  f32x16 __attribute__((ext_vector_type(16)));

__device__ __forceinline__ float wred_max(float v){
#pragma unroll
  for (int m = 1; m < 64; m <<= 1) v = fmaxf(v, __shfl_xor(v, m, 64));
  return v;
}
__device__ __forceinline__ float wred_sum(float v){
#pragma unroll
  for (int m = 1; m < 64; m <<= 1) v += __shfl_xor(v, m, 64);
  return v;
}
__device__ __forceinline__ float digamma_f(float x){
  float r = 0.f;
  while (x < 6.f){ r -= 1.f/x; x += 1.f; }
  float ix = 1.f/x, ix2 = ix*ix;
  return r + logf(x) - 0.5f*ix - ix2*(0.0833333333f - ix2*(0.0083333333f - ix2*0.0039682540f));
}

// grid barrier: 256 blocks co-resident (1 block/CU guaranteed: 50.7KB LDS < 160KB).
// Relaxed RMW poll (no per-poll cache invalidate; R2 lesson) + one acquire fence.
__device__ __forceinline__ void gridbar(int* cnt){
  __syncthreads();
  if (threadIdx.x == 0){
    __hip_atomic_fetch_add(cnt, 1, __ATOMIC_ACQ_REL, __HIP_MEMORY_SCOPE_AGENT);
    while (__hip_atomic_fetch_add(cnt, 0, __ATOMIC_RELAXED, __HIP_MEMORY_SCOPE_AGENT) < NB)
      __builtin_amdgcn_s_sleep(16);
    __builtin_amdgcn_fence(__ATOMIC_ACQUIRE, "agent");
  }
  __syncthreads();
}

// ---------------- Neumann inverse + logdet + ElogA/P/PT (zeroes barrier counters) ----------------
__global__ void __launch_bounds__(256, 1) k_neumann(
    const float* __restrict__ Psi, const float* __restrict__ niw_mu,
    const float* __restrict__ nu_, const float* __restrict__ phi,
    __bf16* __restrict__ Ebf, float* __restrict__ EdiagT,
    float* __restrict__ cvecT, float* __restrict__ rK, float* __restrict__ Lhalf,
    float* __restrict__ sclK,
    float* __restrict__ ElogA, float* __restrict__ P, float* __restrict__ PT,
    int* __restrict__ syncb)
{
  extern __shared__ float lds[];
  float* Rl = lds;            // [DD][RS]
  float* Pb = lds + DD*RS;    // [DD][RS]
  __shared__ float red[256];
  __shared__ float msh[DD];
  int k = blockIdx.x, tid = threadIdx.x;
  const float* A = Psi + (size_t)k*DD*DD;

  if (k == 0 && tid < 16)
    __hip_atomic_store(&syncb[tid], 0, __ATOMIC_RELAXED, __HIP_MEMORY_SCOPE_AGENT);

  if (tid < 64){
    float ph = phi[k*KK + tid];
    float s  = wred_sum(ph);
    float e  = digamma_f(ph) - digamma_f(s);
    ElogA[k*KK + tid] = e;
    float p = expf(e);
    P [k*KK + tid] = p;
    PT[tid*KK + k] = p;
  }

  float tl = 0.f;
  for (int d = tid; d < DD; d += 256) tl += A[d*DD + d];
  red[tid] = tl; __syncthreads();
  for (int off = 128; off > 0; off >>= 1){ if (tid < off) red[tid] += red[tid+off]; __syncthreads(); }
  float c = red[0] / (float)DD;
  __syncthreads();

  float trpow = 0.f;
  for (int idx = tid; idx < DD*DD; idx += 256){
    int d = idx >> 7, e = idx & 127;
    float v = ((d == e) ? 1.f : 0.f) - A[idx]/c;
    Rl[d*RS + e] = v;
    if (d == e) trpow += v;
  }
  __syncthreads();

  int tr = tid >> 4, tc = tid & 15;
  int r0 = tr*8, c0 = tc*8;
  float S[8][8];
#pragma unroll
  for (int i = 0; i < 8; i++)
#pragma unroll
    for (int j = 0; j < 8; j++){
      float v = Rl[(r0+i)*RS + c0+j];
      if (r0+i == c0+j) v += 1.f;
      S[i][j] = v;
    }

  {
    float Cc[8][8];
#pragma unroll
    for (int i = 0; i < 8; i++)
#pragma unroll
      for (int j = 0; j < 8; j++) Cc[i][j] = 0.f;
    for (int l = 0; l < DD; l += 4){
      float af[4][8], bf[4][8];
#pragma unroll
      for (int q = 0; q < 4; q++){
        float4 x0 = *(const float4*)&Rl[(l+q)*RS + r0];
        float4 x1 = *(const float4*)&Rl[(l+q)*RS + r0 + 4];
        af[q][0]=x0.x; af[q][1]=x0.y; af[q][2]=x0.z; af[q][3]=x0.w;
        af[q][4]=x1.x; af[q][5]=x1.y; af[q][6]=x1.z; af[q][7]=x1.w;
        float4 y0 = *(const float4*)&Rl[(l+q)*RS + c0];
        float4 y1 = *(const float4*)&Rl[(l+q)*RS + c0 + 4];
        bf[q][0]=y0.x; bf[q][1]=y0.y; bf[q][2]=y0.z; bf[q][3]=y0.w;
        bf[q][4]=y1.x; bf[q][5]=y1.y; bf[q][6]=y1.z; bf[q][7]=y1.w;
      }
#pragma unroll
      for (int q = 0; q < 4; q++)
#pragma unroll
        for (int i = 0; i < 8; i++)
#pragma unroll
          for (int j = 0; j < 8; j++)
            Cc[i][j] = fmaf(af[q][i], bf[q][j], Cc[i][j]);
    }
#pragma unroll
    for (int i = 0; i < 8; i++)
#pragma unroll
      for (int j = 0; j < 8; j++) S[i][j] += Cc[i][j];
    if (tr == tc){
#pragma unroll
      for (int i = 0; i < 8; i++) trpow += Cc[i][i]*0.5f;
    }
  }

  red[tid] = trpow; __syncthreads();
  for (int off = 128; off > 0; off >>= 1){ if (tid < off) red[tid] += red[tid+off]; __syncthreads(); }
  float trsum = red[0];
  __syncthreads();

  float nu = nu_[k];
  float dl = 0.f;
  for (int i = tid; i < DD; i += 256) dl += digamma_f((nu - (float)i)*0.5f);
  red[tid] = dl; __syncthreads();
  for (int off = 128; off > 0; off >>= 1){ if (tid < off) red[tid] += red[tid+off]; __syncthreads(); }
  if (tid == 0){
    float logdetPsi = (float)DD*logf(c) - trsum;
    float Elogdet = red[0] + (float)DD*0.69314718056f - logdetPsi;
    Lhalf[k] = 0.5f*Elogdet - 0.5f*(float)DD*1.83787706641f;
    sclK[k]  = nu / c;
  }
  __syncthreads();

  float scl = nu / c;
#pragma unroll
  for (int i = 0; i < 8; i++)
#pragma unroll
    for (int j = 0; j < 8; j++){
      float sv = S[i][j];
      bool dg = (r0+i == c0+j);
      if (dg) EdiagT[(r0+i)*KK + k] = scl*sv;
      float et = scl*(sv - (dg ? 1.f : 0.f));
      int r = (r0+i)*DD + (c0+j);
      Ebf[(size_t)(r>>4)*1024 + k*16 + (r&15)] = (__bf16)et;
    }
#pragma unroll
  for (int i = 0; i < 8; i++){
    float4 w0, w1;
    w0.x=S[i][0]; w0.y=S[i][1]; w0.z=S[i][2]; w0.w=S[i][3];
    w1.x=S[i][4]; w1.y=S[i][5]; w1.z=S[i][6]; w1.w=S[i][7];
    *(float4*)&Pb[(r0+i)*RS + c0]     = w0;
    *(float4*)&Pb[(r0+i)*RS + c0 + 4] = w1;
  }
  for (int d = tid; d < DD; d += 256) msh[d] = niw_mu[k*DD + d];
  __syncthreads();
  float cv = 0.f;
  if (tid < DD){
    float acc = 0.f;
    for (int e = 0; e < DD; e++) acc += Pb[tid*RS + e]*msh[e];
    cv = scl*acc;
    cvecT[tid*KK + k] = cv;
  }
  red[tid] = (tid < DD) ? msh[tid]*cv : 0.f; __syncthreads();
  for (int off = 128; off > 0; off >>= 1){ if (tid < off) red[tid] += red[tid+off]; __syncthreads(); }
  if (tid == 0) rK[k] = red[0];
}

// ---------------- persistent mega-kernel: q1 -> logBall -> pass1 -> chain8 -> KSx7 -> pass3 -> outs ----------------
__global__ void __launch_bounds__(256, 1) k_mega(
    const float* __restrict__ mu, const float* __restrict__ dvar,
    const __bf16* __restrict__ Ebf,
    const float* __restrict__ cvecT, const float* __restrict__ EdiagT,
    const float* __restrict__ rK, const float* __restrict__ Lhalf, const float* __restrict__ sclK,
    const float* __restrict__ Pm, const float* __restrict__ PTm,
    const float* __restrict__ ElogA, const float* __restrict__ log_pi,
    float* __restrict__ logB, float* __restrict__ mrow, float* __restrict__ btil,
    float* G8, float* __restrict__ H64,
    float* __restrict__ ah, float* __restrict__ bh, float* __restrict__ llp,
    float* __restrict__ out_rhat, float* __restrict__ out_xi, float* __restrict__ out_ll,
    int* __restrict__ syncb)
{
  __shared__ union {
    struct { float muF[32*132]; float trb[128*66]; } q1;
    struct { float G[2][64*GP]; float wmax[2][2][2]; } p1;
    struct { float X[64*GP]; float wmax[2][2]; } c8;
    struct { float X[2][64*GP]; float wmax[2][2]; } ks;
    struct { float la[64]; float wc[64]; float redm[4]; float reds[4]; } os;
  } sh;
  int tid = threadIdx.x, bid = blockIdx.x;
  int w = tid >> 6, lane = tid & 63;

  // ================= Phase Q1: residual quad GEMM =================
  {
    float* muF = sh.q1.muF;
    float* trb = sh.q1.trb;
    int rs = bid & 3, tseg = bid >> 2;
    int t0 = tseg*128, d0 = rs*32;
    int kh = w & 1, th = w >> 1;
    int l31 = lane & 31;
    int k0 = (lane >> 5)*8;

    for (int v = tid; v < 128*32; v += 256){
      int t = v >> 5, d = v & 31;
      muF[d*132 + t] = mu[(size_t)(t0+t)*DD + d0 + d];
    }
    bf16x8 Bf0[8], Bf1[8];
#pragma unroll
    for (int c = 0; c < 8; c++){
      int tc0 = t0 + th*64 + l31;
      int tc1 = tc0 + 32;
      float4 x0 = *(const float4*)&mu[(size_t)tc0*DD + c*16 + k0];
      float4 x1 = *(const float4*)&mu[(size_t)tc0*DD + c*16 + k0 + 4];
      bf16x8 hv;
      hv[0]=(__bf16)x0.x; hv[1]=(__bf16)x0.y; hv[2]=(__bf16)x0.z; hv[3]=(__bf16)x0.w;
      hv[4]=(__bf16)x1.x; hv[5]=(__bf16)x1.y; hv[6]=(__bf16)x1.z; hv[7]=(__bf16)x1.w;
      Bf0[c] = hv;
      float4 y0 = *(const float4*)&mu[(size_t)tc1*DD + c*16 + k0];
      float4 y1 = *(const float4*)&mu[(size_t)tc1*DD + c*16 + k0 + 4];
      bf16x8 gv;
      gv[0]=(__bf16)y0.x; gv[1]=(__bf16)y0.y; gv[2]=(__bf16)y0.z; gv[3]=(__bf16)y0.w;
      gv[4]=(__bf16)y1.x; gv[5]=(__bf16)y1.y; gv[6]=(__bf16)y1.z; gv[7]=(__bf16)y1.w;
      Bf1[c] = gv;
    }
    __syncthreads();

    const unsigned short* Eu = (const unsigned short*)Ebf;
    size_t abase = (size_t)(kh*32 + l31)*16 + k0;
    f32x16 acc0, acc1;
#pragma unroll
    for (int i = 0; i < 16; i++){ acc0[i]=0.f; acc1[i]=0.f; }
    uint4 A0[8], A1[8];
    {
      const unsigned short* ap = Eu + (size_t)d0*8192 + abase;
#pragma unroll
      for (int c = 0; c < 8; c++) A0[c] = *(const uint4*)(ap + c*1024);
#pragma unroll
      for (int c = 0; c < 8; c++) A1[c] = *(const uint4*)(ap + 8192 + c*1024);
    }
    for (int dd = 0; dd < 32; dd += 2){
      {
        f32x16 ta, tb;
#pragma unroll
        for (int i = 0; i < 16; i++){ ta[i]=0.f; tb[i]=0.f; }
#pragma unroll
        for (int c = 0; c < 8; c++){
          bf16x8 av = *(bf16x8*)&A0[c];
          ta = __builtin_amdgcn_mfma_f32_32x32x16_bf16(av, Bf0[c], ta, 0, 0, 0);
          tb = __builtin_amdgcn_mfma_f32_32x32x16_bf16(av, Bf1[c], tb, 0, 0, 0);
        }
        float m0 = muF[dd*132 + th*64 + l31];
        float m1 = muF[dd*132 + th*64 + 32 + l31];
#pragma unroll
        for (int i = 0; i < 16; i++){
          acc0[i] = fmaf(m0, ta[i], acc0[i]);
          acc1[i] = fmaf(m1, tb[i], acc1[i]);
        }
      }
      if (dd + 2 < 32){
        const unsigned short* ap = Eu + (size_t)(d0+dd+2)*8192 + abase;
#pragma unroll
        for (int c = 0; c < 8; c++) A0[c] = *(const uint4*)(ap + c*1024);
      }
      {
        f32x16 ta, tb;
#pragma unroll
        for (int i = 0; i < 16; i++){ ta[i]=0.f; tb[i]=0.f; }
#pragma unroll
        for (int c = 0; c < 8; c++){
          bf16x8 av = *(bf16x8*)&A1[c];
          ta = __builtin_amdgcn_mfma_f32_32x32x16_bf16(av, Bf0[c], ta, 0, 0, 0);
          tb = __builtin_amdgcn_mfma_f32_32x32x16_bf16(av, Bf1[c], tb, 0, 0, 0);
        }
        float m0 = muF[(dd+1)*132 + th*64 + l31];
        float m1 = muF[(dd+1)*132 + th*64 + 32 + l31];
#pragma unroll
        for (int i = 0; i < 16; i++){
          acc0[i] = fmaf(m0, ta[i], acc0[i]);
          acc1[i] = fmaf(m1, tb[i], acc1[i]);
        }
      }
      if (dd + 3 < 32){
        const unsigned short* ap = Eu + (size_t)(d0+dd+3)*8192 + abase;
#pragma unroll
        for (int c = 0; c < 8; c++) A1[c] = *(const uint4*)(ap + c*1024);
      }
    }
    __syncthreads();
#pragma unroll
    for (int r = 0; r < 16; r++){
      int krow = kh*32 + (r&3) + 8*(r>>2) + 4*(lane>>5);
      trb[(th*64 + l31)*66 + krow]      = acc0[r];
      trb[(th*64 + 32 + l31)*66 + krow] = acc1[r];
    }
    __syncthreads();
    float* dst = G8 + (size_t)rs*T_LEN*KK;   // part alias
    {
      int t = tid >> 1, kc = (tid & 1)*32;
#pragma unroll
      for (int q = 0; q < 8; q++){
        float4 vv = *(float4*)&trb[t*66 + kc + q*4];
        *(float4*)&dst[(size_t)(t0+t)*KK + kc + q*4] = vv;
      }
    }
  }
  gridbar(&syncb[0]);

  // ================= Phase logBall =================
  {
    const float* part = G8;
    int k = lane;
    float rk = rK[k], lh = Lhalf[k], scl = sclK[k];
    int tbase = bid*32 + w*8;
    float a1[8], a2[8], ssv[8];
#pragma unroll
    for (int tt = 0; tt < 8; tt++){ a1[tt]=0.f; a2[tt]=0.f; ssv[tt]=0.f; }
    for (int dc = 0; dc < DD; dc += 4){
      float c0 = cvecT[(dc+0)*KK + k], c1 = cvecT[(dc+1)*KK + k];
      float c2 = cvecT[(dc+2)*KK + k], c3 = cvecT[(dc+3)*KK + k];
      float e0 = EdiagT[(dc+0)*KK + k], e1 = EdiagT[(dc+1)*KK + k];
      float e2 = EdiagT[(dc+2)*KK + k], e3 = EdiagT[(dc+3)*KK + k];
#pragma unroll
      for (int tt = 0; tt < 8; tt++){
        float4 m4 = *(const float4*)(mu   + (size_t)(tbase+tt)*DD + dc);
        float4 v4 = *(const float4*)(dvar + (size_t)(tbase+tt)*DD + dc);
        a1[tt] = fmaf(m4.x,c0, fmaf(m4.y,c1, fmaf(m4.z,c2, fmaf(m4.w,c3, a1[tt]))));
        a2[tt] = fmaf(fmaxf(v4.x,0.f),e0, fmaf(fmaxf(v4.y,0.f),e1,
                 fmaf(fmaxf(v4.z,0.f),e2, fmaf(fmaxf(v4.w,0.f),e3, a2[tt]))));
        ssv[tt] = fmaf(m4.x,m4.x, fmaf(m4.y,m4.y, fmaf(m4.z,m4.z, fmaf(m4.w,m4.w, ssv[tt]))));
      }
    }
#pragma unroll
    for (int tt = 0; tt < 8; tt++){
      int t = tbase + tt;
      float q = scl*ssv[tt]
              + part[(size_t)0*T_LEN*KK + (size_t)t*KK + k]
              + part[(size_t)1*T_LEN*KK + (size_t)t*KK + k]
              + part[(size_t)2*T_LEN*KK + (size_t)t*KK + k]
              + part[(size_t)3*T_LEN*KK + (size_t)t*KK + k];
      float lb = lh - 0.5f*(q - 2.f*a1[tt] + rk + a2[tt]);
      float m  = wred_max(lb);
      logB[(size_t)t*KK + k] = lb;
      btil[(size_t)t*KK + k] = expf(lb - m);
      if (k == 0) mrow[t] = m;
    }
  }
  gridbar(&syncb[1]);

  // ================= Phase pass1: 1024 chunk operators (2 half-blocks x 2 iters) =================
  {
    int half = tid >> 7, htid = tid & 127;
    int hw = htid >> 6, hlane = htid & 63;
    int kb8 = (hlane >> 5)*8;
    int n = hlane & 31;
    bf16x8 Bhi[4][2], Blo[4][2];
#pragma unroll
    for (int Kb = 0; Kb < 4; Kb++)
#pragma unroll
      for (int J = 0; J < 2; J++){
#pragma unroll
        for (int j = 0; j < 8; j++){
          float p = Pm[(Kb*16 + kb8 + j)*KK + J*32 + n];
          __bf16 h = (__bf16)p;
          Bhi[Kb][J][j] = h;
          Blo[Kb][J][j] = (__bf16)(p - (float)h);
        }
      }
    float* G = sh.p1.G[half];
    int m = hw*32 + n;
    for (int it = 0; it < 2; it++){
      int chunk = bid*4 + half*2 + it;
      for (int v = htid; v < 64*64; v += 128){
        int i = v >> 6, j = v & 63;
        G[i*GP + j] = (i == j) ? 1.f : 0.f;
      }
      __syncthreads();
      for (int s = 0; s < 8; s++){
        int t = chunk*8 + s;
        bool dowork = (t >= 1);
        f32x16 acc0, acc1;
        if (dowork){
#pragma unroll
          for (int i = 0; i < 16; i++){ acc0[i] = 0.f; acc1[i] = 0.f; }
#pragma unroll
          for (int Kb = 0; Kb < 4; Kb++){
            float4 x0 = *(const float4*)&G[m*GP + Kb*16 + kb8];
            float4 x1 = *(const float4*)&G[m*GP + Kb*16 + kb8 + 4];
            float xv[8] = {x0.x,x0.y,x0.z,x0.w,x1.x,x1.y,x1.z,x1.w};
            bf16x8 ahv, alv;
#pragma unroll
            for (int j = 0; j < 8; j++){
              __bf16 h = (__bf16)xv[j];
              ahv[j] = h;
              alv[j] = (__bf16)(xv[j] - (float)h);
            }
            acc0 = __builtin_amdgcn_mfma_f32_32x32x16_bf16(ahv, Bhi[Kb][0], acc0, 0,0,0);
            acc0 = __builtin_amdgcn_mfma_f32_32x32x16_bf16(ahv, Blo[Kb][0], acc0, 0,0,0);
            acc0 = __builtin_amdgcn_mfma_f32_32x32x16_bf16(alv, Bhi[Kb][0], acc0, 0,0,0);
            acc1 = __builtin_amdgcn_mfma_f32_32x32x16_bf16(ahv, Bhi[Kb][1], acc1, 0,0,0);
            acc1 = __builtin_amdgcn_mfma_f32_32x32x16_bf16(ahv, Blo[Kb][1], acc1, 0,0,0);
            acc1 = __builtin_amdgcn_mfma_f32_32x32x16_bf16(alv, Bhi[Kb][1], acc1, 0,0,0);
          }
          float b0 = btil[(size_t)t*KK + n];
          float b1 = btil[(size_t)t*KK + 32 + n];
          float mx = 0.f;
#pragma unroll
          for (int i = 0; i < 16; i++){
            acc0[i] *= b0; acc1[i] *= b1;
            mx = fmaxf(mx, fmaxf(acc0[i], acc1[i]));
          }
          mx = wred_max(mx);
          if (hlane == 0) sh.p1.wmax[half][s&1][hw] = mx;
        }
        __syncthreads();
        if (dowork){
          float inv = 1.f/fmaxf(sh.p1.wmax[half][s&1][0], sh.p1.wmax[half][s&1][1]);
#pragma unroll
          for (int r = 0; r < 16; r++){
            int row = hw*32 + (r&3) + 8*(r>>2) + 4*(hlane>>5);
            G[row*GP + n]      = acc0[r]*inv;
            G[row*GP + 32 + n] = acc1[r]*inv;
          }
        }
      }
      __syncthreads();
      float* dst = G8 + (size_t)chunk*4096;
      for (int v = htid; v < 4096; v += 128) dst[v] = G[(v>>6)*GP + (v&63)];
      __syncthreads();
    }
  }
  gridbar(&syncb[2]);

  // ================= Phase chain8: G8 -> H64 (blocks 0..127) =================
  if (bid < 128){
    float* X = sh.c8.X;
    const float* s0 = G8 + (size_t)bid*8*4096;
    bool act = (w < 2);
    int kb8 = (lane >> 5)*8;
    int n = lane & 31;
    int m = w*32 + n;
    for (int v = tid; v < 4096; v += 256) X[(v>>6)*GP + (v&63)] = s0[v];
    __syncthreads();
    for (int j = 1; j < 8; j++){
      const float* Y = s0 + (size_t)j*4096;
      f32x16 acc0, acc1;
      if (act){
        bf16x8 Bh[4][2], Bl[4][2];
#pragma unroll
        for (int Kb = 0; Kb < 4; Kb++)
#pragma unroll
          for (int J = 0; J < 2; J++){
#pragma unroll
            for (int jj = 0; jj < 8; jj++){
              float p = Y[(Kb*16 + kb8 + jj)*64 + J*32 + n];
              __bf16 h = (__bf16)p;
              Bh[Kb][J][jj] = h;
              Bl[Kb][J][jj] = (__bf16)(p - (float)h);
            }
          }
#pragma unroll
        for (int i = 0; i < 16; i++){ acc0[i] = 0.f; acc1[i] = 0.f; }
#pragma unroll
        for (int Kb = 0; Kb < 4; Kb++){
          float4 x0 = *(const float4*)&X[m*GP + Kb*16 + kb8];
          float4 x1 = *(const float4*)&X[m*GP + Kb*16 + kb8 + 4];
          float xv[8] = {x0.x,x0.y,x0.z,x0.w,x1.x,x1.y,x1.z,x1.w};
          bf16x8 ahv, alv;
#pragma unroll
          for (int q = 0; q < 8; q++){
            __bf16 h = (__bf16)xv[q];
            ahv[q] = h;
            alv[q] = (__bf16)(xv[q] - (float)h);
          }
          acc0 = __builtin_amdgcn_mfma_f32_32x32x16_bf16(ahv, Bh[Kb][0], acc0, 0,0,0);
          acc0 = __builtin_amdgcn_mfma_f32_32x32x16_bf16(ahv, Bl[Kb][0], acc0, 0,0,0);
          acc0 = __builtin_amdgcn_mfma_f32_32x32x16_bf16(alv, Bh[Kb][0], acc0, 0,0,0);
          acc1 = __builtin_amdgcn_mfma_f32_32x32x16_bf16(ahv, Bh[Kb][1], acc1, 0,0,0);
          acc1 = __builtin_amdgcn_mfma_f32_32x32x16_bf16(ahv, Bl[Kb][1], acc1, 0,0,0);
          acc1 = __builtin_amdgcn_mfma_f32_32x32x16_bf16(alv, Bh[Kb][1], acc1, 0,0,0);
        }
        float mx = 0.f;
#pragma unroll
        for (int i = 0; i < 16; i++) mx = fmaxf(mx, fmaxf(acc0[i], acc1[i]));
        mx = wred_max(mx);
        if (lane == 0) sh.c8.wmax[j&1][w] = mx;
      }
      __syncthreads();
      if (act){
        float inv = 1.f/fmaxf(sh.c8.wmax[j&1][0], sh.c8.wmax[j&1][1]);
#pragma unroll
        for (int r = 0; r < 16; r++){
          int row = w*32 + (r&3) + 8*(r>>2) + 4*(lane>>5);
          X[row*GP + n]      = acc0[r]*inv;
          X[row*GP + 32 + n] = acc1[r]*inv;
        }
      }
      __syncthreads();
    }
    float* dst = H64 + (size_t)bid*4096;
    for (int v = tid; v < 4096; v += 256) dst[v] = X[(v>>6)*GP + (v&63)];
  }
  gridbar(&syncb[3]);

  // ================= KS rounds: waves 0-1 = PA (prefix), waves 2-3 = SB (suffix) =================
  const float* PAfin;
  {
    const size_t MKS = (size_t)128*4096;
    float* PAbuf[2] = {G8, G8 + MKS};
    float* SBbuf[2] = {G8 + 2*MKS, G8 + 3*MKS};
    float* SBT = G8 + 4*MKS;
    const float* PAin = H64; const float* SBin = H64;
    int cur = 1;
    int side = tid >> 7, htid = tid & 127;
    int sw = (tid >> 6) & 1;
    int n = lane & 31;
    int kb8 = (lane >> 5)*8;
    int m = sw*32 + n;
    for (int r = 0; r < 7; r++){
      int s = 1 << r;
      int wrT = (r == 6);
      if (bid < 128){
        int c = bid;
        bool comb;
        const float *Asrc, *Bsrc; float* out;
        if (side == 0){
          comb = (c >= s);
          Asrc = comb ? (PAin + (size_t)(c-s)*4096) : (PAin + (size_t)c*4096);
          Bsrc = PAin + (size_t)c*4096;
          out  = PAbuf[cur] + (size_t)c*4096;
        } else {
          comb = (c + s <= 127);
          Asrc = SBin + (size_t)c*4096;
          Bsrc = comb ? (SBin + (size_t)(c+s)*4096) : (SBin + (size_t)c*4096);
          out  = SBbuf[cur] + (size_t)c*4096;
        }
        float* Xs = sh.ks.X[side];
        for (int v = htid; v < 4096; v += 128) Xs[(v>>6)*GP + (v&63)] = Asrc[v];
        bf16x8 Bh[4][2], Bl[4][2];
        if (comb){
#pragma unroll
          for (int Kb = 0; Kb < 4; Kb++)
#pragma unroll
            for (int J = 0; J < 2; J++){
#pragma unroll
              for (int jj = 0; jj < 8; jj++){
                float p = Bsrc[(Kb*16 + kb8 + jj)*64 + J*32 + n];
                __bf16 h = (__bf16)p;
                Bh[Kb][J][jj] = h;
                Bl[Kb][J][jj] = (__bf16)(p - (float)h);
              }
            }
        }
        __syncthreads();
        f32x16 acc0, acc1;
        if (comb){
#pragma unroll
          for (int i = 0; i < 16; i++){ acc0[i] = 0.f; acc1[i] = 0.f; }
#pragma unroll
          for (int Kb = 0; Kb < 4; Kb++){
            float4 x0 = *(const float4*)&Xs[m*GP + Kb*16 + kb8];
            float4 x1 = *(const float4*)&Xs[m*GP + Kb*16 + kb8 + 4];
            float xv[8] = {x0.x,x0.y,x0.z,x0.w,x1.x,x1.y,x1.z,x1.w};
            bf16x8 ahv, alv;
#pragma unroll
            for (int q = 0; q < 8; q++){
              __bf16 h = (__bf16)xv[q];
              ahv[q] = h;
              alv[q] = (__bf16)(xv[q] - (float)h);
            }
            acc0 = __builtin_amdgcn_mfma_f32_32x32x16_bf16(ahv, Bh[Kb][0], acc0, 0,0,0);
            acc0 = __builtin_amdgcn_mfma_f32_32x32x16_bf16(ahv, Bl[Kb][0], acc0, 0,0,0);
            acc0 = __builtin_amdgcn_mfma_f32_32x32x16_bf16(alv, Bh[Kb][0], acc0, 0,0,0);
            acc1 = __builtin_amdgcn_mfma_f32_32x32x16_bf16(ahv, Bh[Kb][1], acc1, 0,0,0);
            acc1 = __builtin_amdgcn_mfma_f32_32x32x16_bf16(ahv, Bl[Kb][1], acc1, 0,0,0);
            acc1 = __builtin_amdgcn_mfma_f32_32x32x16_bf16(alv, Bh[Kb][1], acc1, 0,0,0);
          }
          float mx = 0.f;
#pragma unroll
          for (int i = 0; i < 16; i++) mx = fmaxf(mx, fmaxf(acc0[i], acc1[i]));
          mx = wred_max(mx);
          if (lane == 0) sh.ks.wmax[side][sw] = mx;
        }
        __syncthreads();
        if (comb){
          float inv = 1.f/fmaxf(sh.ks.wmax[side][0], sh.ks.wmax[side][1]);
#pragma unroll
          for (int r2 = 0; r2 < 16; r2++){
            int row = sw*32 + (r2&3) + 8*(r2>>2) + 4*(lane>>5);
            out[row*64 + n]      = acc0[r2]*inv;
            out[row*64 + 32 + n] = acc1[r2]*inv;
            if (wrT && side == 1){
              Xs[row*GP + n]      = acc0[r2]*inv;
              Xs[row*GP + 32 + n] = acc1[r2]*inv;
            }
          }
        } else {
          for (int v = htid; v < 4096; v += 128) out[v] = Xs[(v>>6)*GP + (v&63)];
        }
        if (wrT){
          __syncthreads();
          if (side == 1){
            float* ot = SBT + (size_t)c*4096;
            for (int v = htid; v < 4096; v += 128) ot[v] = Xs[(v&63)*GP + (v>>6)];
          }
        }
      }
      gridbar(&syncb[4 + r]);
      PAin = PAbuf[cur]; SBin = SBbuf[cur]; cur ^= 1;
    }
    PAfin = PAin;

    // ================= Phase pass3: per-64-chunk recurrences (64 blocks x 4 waves) =================
    if (bid < 64){
      int vb = bid*4 + w;
      if (vb < 128){
        int c = vb;
        float Preg[64];
#pragma unroll
        for (int i = 0; i < 64; i++) Preg[i] = Pm[i*64 + lane];
        float a; float llacc = 0.f;
        int tstart;
        float x0v = log_pi[lane] + logB[lane];
        float mm0 = wred_max(x0v);
        float e0 = expf(x0v - mm0);
        float ss0 = wred_sum(e0);
        if (c == 0){
          a = e0/ss0;
          llacc = mm0 + logf(ss0);
          ah[lane] = a;
          tstart = 1;
        } else {
          float a0 = e0/ss0;
          const float* H = PAfin + (size_t)(c-1)*4096;
          float Hr[64];
#pragma unroll
          for (int i = 0; i < 64; i++) Hr[i] = H[i*64 + lane];
          float p0 = 0.f, p1 = 0.f, p2 = 0.f, p3 = 0.f;
#pragma unroll
          for (int i = 0; i < 16; i++){
            p0 = fmaf(__shfl(a0, i,      64), Hr[i],      p0);
            p1 = fmaf(__shfl(a0, i + 16, 64), Hr[i + 16], p1);
            p2 = fmaf(__shfl(a0, i + 32, 64), Hr[i + 32], p2);
            p3 = fmaf(__shfl(a0, i + 48, 64), Hr[i + 48], p3);
          }
          a = (p0 + p1) + (p2 + p3);
          a /= wred_sum(a);
          tstart = c*64;
        }
        int tend = c*64 + 64;
        float bt = btil[(size_t)tstart*KK + lane];
        for (int t = tstart; t < tend; t++){
          float btn = 0.f;
          if (t + 1 < tend) btn = btil[(size_t)(t+1)*KK + lane];
          float mr = mrow[t];
          float p0 = 0.f, p1 = 0.f, p2 = 0.f, p3 = 0.f;
#pragma unroll
          for (int i = 0; i < 16; i++){
            p0 = fmaf(__shfl(a, i,      64), Preg[i],      p0);
            p1 = fmaf(__shfl(a, i + 16, 64), Preg[i + 16], p1);
            p2 = fmaf(__shfl(a, i + 32, 64), Preg[i + 32], p2);
            p3 = fmaf(__shfl(a, i + 48, 64), Preg[i + 48], p3);
          }
          float pred = (p0 + p1) + (p2 + p3);
          a = pred * bt;
          if (((t - tstart) & 3) == 3 || t == tend - 1){
            float s = wred_sum(a);
            a = a / s;
            llacc += logf(s);
          }
          llacc += mr;
          ah[(size_t)t*KK + lane] = a;
          bt = btn;
        }
        if (lane == 0) llp[c] = llacc;
      } else {
        int c = vb - 128;
        const float* SBT = G8 + 4*(size_t)128*4096;
        float PTreg[64];
#pragma unroll
        for (int j = 0; j < 64; j++) PTreg[j] = PTm[j*64 + lane];
        float b, lb;
        if (c == 127){
          b = 1.f; lb = 0.f;
        } else {
          const float* H = SBT + (size_t)(c+1)*4096;
          float s0 = 0.f, s1 = 0.f, s2 = 0.f, s3 = 0.f;
#pragma unroll
          for (int i = 0; i < 16; i++){
            s0 += H[(i     )*64 + lane];
            s1 += H[(i + 16)*64 + lane];
            s2 += H[(i + 32)*64 + lane];
            s3 += H[(i + 48)*64 + lane];
          }
          float s = (s0 + s1) + (s2 + s3);
          float mmb = wred_max(s);
          b = s/mmb;
          lb = logf(b);
        }
        int t1 = c*64 + 63;
        bh[(size_t)t1*KK + lane] = b;
        float lgb = logB[(size_t)t1*KK + lane];
        float mrn = mrow[t1];
        for (int t = t1 - 1; t >= c*64; t--){
          float lgbn = 0.f, mrnn = 0.f;
          if (t > c*64){
            lgbn = logB[(size_t)t*KK + lane];
            mrnn = mrow[t];
          }
          float lv = (lgb - mrn) + lb;
          float vm = wred_max(lv);
          float vv = expf(lv - vm);
          float q0 = 0.f, q1r = 0.f, q2 = 0.f, q3 = 0.f;
#pragma unroll
          for (int j = 0; j < 16; j++){
            q0  = fmaf(PTreg[j],      __shfl(vv, j,      64), q0);
            q1r = fmaf(PTreg[j + 16], __shfl(vv, j + 16, 64), q1r);
            q2  = fmaf(PTreg[j + 32], __shfl(vv, j + 32, 64), q2);
            q3  = fmaf(PTreg[j + 48], __shfl(vv, j + 48, 64), q3);
          }
          b = (q0 + q1r) + (q2 + q3);
          lb = logf(b);
          bh[(size_t)t*KK + lane] = b;
          lgb = lgbn; mrn = mrnn;
        }
      }
    }
  }
  gridbar(&syncb[11]);

  // ================= Phase outs: rhat + xihat + ll (32 rows per block) =================
  for (int it = 0; it < 32; it++){
    int b = bid + it*256;
    if (tid < 64) sh.os.la[tid] = logf(ah[(size_t)b*KK + tid]);
    else if (tid < 128 && b < T_LEN-1){
      int j = tid - 64;
      sh.os.wc[j] = logB[(size_t)(b+1)*KK + j] + logf(bh[(size_t)(b+1)*KK + j]);
    }
    __syncthreads();
    if (tid < 64){
      float s = sh.os.la[tid] + logf(bh[(size_t)b*KK + tid]);
      float m = wred_max(s);
      float p = (m < -3.0e37f) ? 1.f : expf(s - m);
      float ss = wred_sum(p);
      out_rhat[(size_t)b*KK + tid] = p/ss;
    }
    if (b == T_LEN-1){
      if (tid >= 64 && tid < 128){
        int i = tid - 64;
        float v = llp[i] + llp[i + 64];
        v = wred_sum(v);
        if (i == 0) out_ll[0] = v;
      }
    } else {
      int j0 = (lane & 15) << 2;
      int ibase = w*16 + (lane >> 4)*4;
      float4 wc4 = *(float4*)&sh.os.wc[j0];
      float sv[16];
      float mx = -3.0e38f;
#pragma unroll
      for (int ii = 0; ii < 4; ii++){
        float lai = sh.os.la[ibase + ii];
        float4 e4 = *(const float4*)&ElogA[(ibase+ii)*KK + j0];
        float s0 = lai + e4.x + wc4.x;
        float s1 = lai + e4.y + wc4.y;
        float s2 = lai + e4.z + wc4.z;
        float s3 = lai + e4.w + wc4.w;
        sv[ii*4+0]=s0; sv[ii*4+1]=s1; sv[ii*4+2]=s2; sv[ii*4+3]=s3;
        mx = fmaxf(fmaxf(fmaxf(mx, s0), fmaxf(s1, s2)), s3);
      }
      float mxw = wred_max(mx);
      if (lane == 0) sh.os.redm[w] = mxw;
      __syncthreads();
      float m = fmaxf(fmaxf(sh.os.redm[0], sh.os.redm[1]), fmaxf(sh.os.redm[2], sh.os.redm[3]));
      bool degen = !(m > -3.0e37f);
      float pv[16]; float ps = 0.f;
#pragma unroll
      for (int nn = 0; nn < 16; nn++){
        float p = degen ? 1.f : expf(sv[nn] - m);
        pv[nn] = p; ps += p;
      }
      float psw = wred_sum(ps);
      if (lane == 0) sh.os.reds[w] = psw;
      __syncthreads();
      float inv = 1.f/(sh.os.reds[0] + sh.os.reds[1] + sh.os.reds[2] + sh.os.reds[3]);
      float* dst = out_xi + (size_t)b*4096;
#pragma unroll
      for (int ii = 0; ii < 4; ii++){
        float4 o;
        o.x = pv[ii*4+0]*inv; o.y = pv[ii*4+1]*inv;
        o.z = pv[ii*4+2]*inv; o.w = pv[ii*4+3]*inv;
        *(float4*)&dst[(ibase+ii)*KK + j0] = o;
      }
    }
    __syncthreads();
  }
}

extern "C" void kernel_launch(void* const* d_in, const int* in_sizes, int n_in,
                              void* d_out, int out_size, void* d_ws, size_t ws_size,
                              hipStream_t stream)
{
  const float* mu    = (const float*)d_in[0];
  const float* dvar  = (const float*)d_in[1];
  const float* niwmu = (const float*)d_in[2];
  const float* Psi   = (const float*)d_in[3];
  const float* nu    = (const float*)d_in[4];
  const float* phi   = (const float*)d_in[5];
  const float* lpi   = (const float*)d_in[6];
  float* out = (float*)d_out;
  float* ws  = (float*)d_ws;

  size_t o = 0;
  float* EbfF   = ws + o; o += (size_t)DD*DD*KK/2;
  float* EdiagT = ws + o; o += (size_t)DD*KK;
  float* cvecT  = ws + o; o += (size_t)DD*KK;
  float* rK     = ws + o; o += KK;
  float* Lhalf  = ws + o; o += KK;
  float* sclK   = ws + o; o += KK;
  float* ElogA  = ws + o; o += KK*KK;
  float* P      = ws + o; o += KK*KK;
  float* PT     = ws + o; o += KK*KK;
  float* logB   = ws + o; o += (size_t)T_LEN*KK;
  float* mrowp  = ws + o; o += T_LEN;
  float* btil   = ws + o; o += (size_t)T_LEN*KK;
  float* G8     = ws + o; o += (size_t)1024*4096;
  float* H64    = ws + o; o += (size_t)128*4096;
  float* llp    = ws + o; o += 128;
  float* ah     = ws + o; o += (size_t)T_LEN*KK;
  float* bh     = ws + o; o += (size_t)T_LEN*KK;
  int*   syncb  = (int*)(ws + o); o += 16;
  if (ws_size < o*sizeof(float)) return;

  __bf16* Ebf = (__bf16*)EbfF;

  hipFuncSetAttribute((const void*)k_neumann, hipFuncAttributeMaxDynamicSharedMemorySize, 2*DD*RS*4);

  k_neumann<<<64, 256, 2*DD*RS*4, stream>>>(Psi, niwmu, nu, phi, Ebf, EdiagT, cvecT, rK, Lhalf, sclK, ElogA, P, PT, syncb);
  k_mega<<<256, 256, 0, stream>>>(mu, dvar, Ebf, cvecT, EdiagT, rK, Lhalf, sclK, P, PT, ElogA, lpi,
                                  logB, mrowp, btil, G8, H64, ah, bh, llp,
                                  out, out + (size_t)T_LEN*KK,
                                  out + (size_t)T_LEN*KK + (size_t)(T_LEN-1)*KK*KK, syncb);
}

// Round 6
// 541.408 us; speedup vs baseline: 1.3106x; 1.3106x over previous
//
#include <hip/hip_runtime.h>
#include <math.h>

#define T_LEN 8192
#define KK 64
#define DD 128
#define RS 132
#define GP 68
#define NB 256

typedef __bf16  bf16x4 __attribute__((ext_vector_type(4)));
typedef __bf16  bf16x8 __attribute__((ext_vector_type(8)));
typedef float  f32x16 __attribute__((ext_vector_type(16)));

__device__ __forceinline__ float wred_max(float v){
#pragma unroll
  for (int m = 1; m < 64; m <<= 1) v = fmaxf(v, __shfl_xor(v, m, 64));
  return v;
}
__device__ __forceinline__ float wred_sum(float v){
#pragma unroll
  for (int m = 1; m < 64; m <<= 1) v += __shfl_xor(v, m, 64);
  return v;
}
__device__ __forceinline__ float digamma_f(float x){
  float r = 0.f;
  while (x < 6.f){ r -= 1.f/x; x += 1.f; }
  float ix = 1.f/x, ix2 = ix*ix;
  return r + logf(x) - 0.5f*ix - ix2*(0.0833333333f - ix2*(0.0083333333f - ix2*0.0039682540f));
}

// grid barrier (relaxed RMW poll, one acquire fence — R2/R3 lesson, proven R4)
__device__ __forceinline__ void gridbar(int* cnt){
  __syncthreads();
  if (threadIdx.x == 0){
    __hip_atomic_fetch_add(cnt, 1, __ATOMIC_ACQ_REL, __HIP_MEMORY_SCOPE_AGENT);
    while (__hip_atomic_fetch_add(cnt, 0, __ATOMIC_RELAXED, __HIP_MEMORY_SCOPE_AGENT) < NB)
      __builtin_amdgcn_s_sleep(32);
    __builtin_amdgcn_fence(__ATOMIC_ACQUIRE, "agent");
  }
  __syncthreads();
}

// ---------------- Neumann inverse + logdet + ElogA/P/PT (zeroes barrier counters) ----------------
__global__ void __launch_bounds__(256, 1) k_neumann(
    const float* __restrict__ Psi, const float* __restrict__ niw_mu,
    const float* __restrict__ nu_, const float* __restrict__ phi,
    __bf16* __restrict__ Ebf, float* __restrict__ EdiagT,
    float* __restrict__ cvecT, float* __restrict__ rK, float* __restrict__ Lhalf,
    float* __restrict__ sclK,
    float* __restrict__ ElogA, float* __restrict__ P, float* __restrict__ PT,
    int* __restrict__ syncb)
{
  extern __shared__ float lds[];
  float* Rl = lds;            // [DD][RS]
  float* Pb = lds + DD*RS;    // [DD][RS]
  __shared__ float red[256];
  __shared__ float msh[DD];
  int k = blockIdx.x, tid = threadIdx.x;
  const float* A = Psi + (size_t)k*DD*DD;

  if (k == 0 && tid < 16)
    __hip_atomic_store(&syncb[tid], 0, __ATOMIC_RELAXED, __HIP_MEMORY_SCOPE_AGENT);

  if (tid < 64){
    float ph = phi[k*KK + tid];
    float s  = wred_sum(ph);
    float e  = digamma_f(ph) - digamma_f(s);
    ElogA[k*KK + tid] = e;
    float p = expf(e);
    P [k*KK + tid] = p;
    PT[tid*KK + k] = p;
  }

  float tl = 0.f;
  for (int d = tid; d < DD; d += 256) tl += A[d*DD + d];
  red[tid] = tl; __syncthreads();
  for (int off = 128; off > 0; off >>= 1){ if (tid < off) red[tid] += red[tid+off]; __syncthreads(); }
  float c = red[0] / (float)DD;
  __syncthreads();

  float trpow = 0.f;
  for (int idx = tid; idx < DD*DD; idx += 256){
    int d = idx >> 7, e = idx & 127;
    float v = ((d == e) ? 1.f : 0.f) - A[idx]/c;
    Rl[d*RS + e] = v;
    if (d == e) trpow += v;
  }
  __syncthreads();

  int tr = tid >> 4, tc = tid & 15;
  int r0 = tr*8, c0 = tc*8;
  float S[8][8];
#pragma unroll
  for (int i = 0; i < 8; i++)
#pragma unroll
    for (int j = 0; j < 8; j++){
      float v = Rl[(r0+i)*RS + c0+j];
      if (r0+i == c0+j) v += 1.f;
      S[i][j] = v;
    }

  {
    float Cc[8][8];
#pragma unroll
    for (int i = 0; i < 8; i++)
#pragma unroll
      for (int j = 0; j < 8; j++) Cc[i][j] = 0.f;
    for (int l = 0; l < DD; l += 4){
      float af[4][8], bf[4][8];
#pragma unroll
      for (int q = 0; q < 4; q++){
        float4 x0 = *(const float4*)&Rl[(l+q)*RS + r0];
        float4 x1 = *(const float4*)&Rl[(l+q)*RS + r0 + 4];
        af[q][0]=x0.x; af[q][1]=x0.y; af[q][2]=x0.z; af[q][3]=x0.w;
        af[q][4]=x1.x; af[q][5]=x1.y; af[q][6]=x1.z; af[q][7]=x1.w;
        float4 y0 = *(const float4*)&Rl[(l+q)*RS + c0];
        float4 y1 = *(const float4*)&Rl[(l+q)*RS + c0 + 4];
        bf[q][0]=y0.x; bf[q][1]=y0.y; bf[q][2]=y0.z; bf[q][3]=y0.w;
        bf[q][4]=y1.x; bf[q][5]=y1.y; bf[q][6]=y1.z; bf[q][7]=y1.w;
      }
#pragma unroll
      for (int q = 0; q < 4; q++)
#pragma unroll
        for (int i = 0; i < 8; i++)
#pragma unroll
          for (int j = 0; j < 8; j++)
            Cc[i][j] = fmaf(af[q][i], bf[q][j], Cc[i][j]);
    }
#pragma unroll
    for (int i = 0; i < 8; i++)
#pragma unroll
      for (int j = 0; j < 8; j++) S[i][j] += Cc[i][j];
    if (tr == tc){
#pragma unroll
      for (int i = 0; i < 8; i++) trpow += Cc[i][i]*0.5f;
    }
  }

  red[tid] = trpow; __syncthreads();
  for (int off = 128; off > 0; off >>= 1){ if (tid < off) red[tid] += red[tid+off]; __syncthreads(); }
  float trsum = red[0];
  __syncthreads();

  float nu = nu_[k];
  float dl = 0.f;
  for (int i = tid; i < DD; i += 256) dl += digamma_f((nu - (float)i)*0.5f);
  red[tid] = dl; __syncthreads();
  for (int off = 128; off > 0; off >>= 1){ if (tid < off) red[tid] += red[tid+off]; __syncthreads(); }
  if (tid == 0){
    float logdetPsi = (float)DD*logf(c) - trsum;
    float Elogdet = red[0] + (float)DD*0.69314718056f - logdetPsi;
    Lhalf[k] = 0.5f*Elogdet - 0.5f*(float)DD*1.83787706641f;
    sclK[k]  = nu / c;
  }
  __syncthreads();

  float scl = nu / c;
#pragma unroll
  for (int i = 0; i < 8; i++)
#pragma unroll
    for (int j = 0; j < 8; j++){
      float sv = S[i][j];
      bool dg = (r0+i == c0+j);
      if (dg) EdiagT[(r0+i)*KK + k] = scl*sv;
      float et = scl*(sv - (dg ? 1.f : 0.f));
      int r = (r0+i)*DD + (c0+j);
      Ebf[(size_t)(r>>4)*1024 + k*16 + (r&15)] = (__bf16)et;
    }
#pragma unroll
  for (int i = 0; i < 8; i++){
    float4 w0, w1;
    w0.x=S[i][0]; w0.y=S[i][1]; w0.z=S[i][2]; w0.w=S[i][3];
    w1.x=S[i][4]; w1.y=S[i][5]; w1.z=S[i][6]; w1.w=S[i][7];
    *(float4*)&Pb[(r0+i)*RS + c0]     = w0;
    *(float4*)&Pb[(r0+i)*RS + c0 + 4] = w1;
  }
  for (int d = tid; d < DD; d += 256) msh[d] = niw_mu[k*DD + d];
  __syncthreads();
  float cv = 0.f;
  if (tid < DD){
    float acc = 0.f;
    for (int e = 0; e < DD; e++) acc += Pb[tid*RS + e]*msh[e];
    cv = scl*acc;
    cvecT[tid*KK + k] = cv;
  }
  red[tid] = (tid < DD) ? msh[tid]*cv : 0.f; __syncthreads();
  for (int off = 128; off > 0; off >>= 1){ if (tid < off) red[tid] += red[tid+off]; __syncthreads(); }
  if (tid == 0) rK[k] = red[0];
}

// ---------------- k_front: q1 (residual quad GEMM) -> gridbar -> logBall ----------------
__global__ void __launch_bounds__(256, 1) k_front(
    const float* __restrict__ mu, const float* __restrict__ dvar,
    const __bf16* __restrict__ Ebf,
    const float* __restrict__ cvecT, const float* __restrict__ EdiagT,
    const float* __restrict__ rK, const float* __restrict__ Lhalf, const float* __restrict__ sclK,
    float* __restrict__ part,
    float* __restrict__ logB, float* __restrict__ mrow, float* __restrict__ btil,
    int* __restrict__ syncb)
{
  __shared__ float muF[32*132];
  __shared__ float trb[128*66];
  int tid = threadIdx.x, bid = blockIdx.x;
  int w = tid >> 6, lane = tid & 63;

  // ===== q1 phase (verbatim R4 k_q1) =====
  {
    int rs = bid & 3, tseg = bid >> 2;
    int t0 = tseg*128, d0 = rs*32;
    int kh = w & 1, th = w >> 1;
    int l31 = lane & 31;
    int k0 = (lane >> 5)*8;

    for (int v = tid; v < 128*32; v += 256){
      int t = v >> 5, d = v & 31;
      muF[d*132 + t] = mu[(size_t)(t0+t)*DD + d0 + d];
    }
    bf16x8 Bf0[8], Bf1[8];
#pragma unroll
    for (int c = 0; c < 8; c++){
      int tc0 = t0 + th*64 + l31;
      int tc1 = tc0 + 32;
      float4 x0 = *(const float4*)&mu[(size_t)tc0*DD + c*16 + k0];
      float4 x1 = *(const float4*)&mu[(size_t)tc0*DD + c*16 + k0 + 4];
      bf16x8 hv;
      hv[0]=(__bf16)x0.x; hv[1]=(__bf16)x0.y; hv[2]=(__bf16)x0.z; hv[3]=(__bf16)x0.w;
      hv[4]=(__bf16)x1.x; hv[5]=(__bf16)x1.y; hv[6]=(__bf16)x1.z; hv[7]=(__bf16)x1.w;
      Bf0[c] = hv;
      float4 y0 = *(const float4*)&mu[(size_t)tc1*DD + c*16 + k0];
      float4 y1 = *(const float4*)&mu[(size_t)tc1*DD + c*16 + k0 + 4];
      bf16x8 gv;
      gv[0]=(__bf16)y0.x; gv[1]=(__bf16)y0.y; gv[2]=(__bf16)y0.z; gv[3]=(__bf16)y0.w;
      gv[4]=(__bf16)y1.x; gv[5]=(__bf16)y1.y; gv[6]=(__bf16)y1.z; gv[7]=(__bf16)y1.w;
      Bf1[c] = gv;
    }
    __syncthreads();

    const unsigned short* Eu = (const unsigned short*)Ebf;
    size_t abase = (size_t)(kh*32 + l31)*16 + k0;
    f32x16 acc0, acc1;
#pragma unroll
    for (int i = 0; i < 16; i++){ acc0[i]=0.f; acc1[i]=0.f; }
    uint4 A0[8], A1[8];
    {
      const unsigned short* ap = Eu + (size_t)d0*8192 + abase;
#pragma unroll
      for (int c = 0; c < 8; c++) A0[c] = *(const uint4*)(ap + c*1024);
#pragma unroll
      for (int c = 0; c < 8; c++) A1[c] = *(const uint4*)(ap + 8192 + c*1024);
    }
    for (int dd = 0; dd < 32; dd += 2){
      {
        f32x16 ta, tb;
#pragma unroll
        for (int i = 0; i < 16; i++){ ta[i]=0.f; tb[i]=0.f; }
#pragma unroll
        for (int c = 0; c < 8; c++){
          bf16x8 av = *(bf16x8*)&A0[c];
          ta = __builtin_amdgcn_mfma_f32_32x32x16_bf16(av, Bf0[c], ta, 0, 0, 0);
          tb = __builtin_amdgcn_mfma_f32_32x32x16_bf16(av, Bf1[c], tb, 0, 0, 0);
        }
        float m0 = muF[dd*132 + th*64 + l31];
        float m1 = muF[dd*132 + th*64 + 32 + l31];
#pragma unroll
        for (int i = 0; i < 16; i++){
          acc0[i] = fmaf(m0, ta[i], acc0[i]);
          acc1[i] = fmaf(m1, tb[i], acc1[i]);
        }
      }
      if (dd + 2 < 32){
        const unsigned short* ap = Eu + (size_t)(d0+dd+2)*8192 + abase;
#pragma unroll
        for (int c = 0; c < 8; c++) A0[c] = *(const uint4*)(ap + c*1024);
      }
      {
        f32x16 ta, tb;
#pragma unroll
        for (int i = 0; i < 16; i++){ ta[i]=0.f; tb[i]=0.f; }
#pragma unroll
        for (int c = 0; c < 8; c++){
          bf16x8 av = *(bf16x8*)&A1[c];
          ta = __builtin_amdgcn_mfma_f32_32x32x16_bf16(av, Bf0[c], ta, 0, 0, 0);
          tb = __builtin_amdgcn_mfma_f32_32x32x16_bf16(av, Bf1[c], tb, 0, 0, 0);
        }
        float m0 = muF[(dd+1)*132 + th*64 + l31];
        float m1 = muF[(dd+1)*132 + th*64 + 32 + l31];
#pragma unroll
        for (int i = 0; i < 16; i++){
          acc0[i] = fmaf(m0, ta[i], acc0[i]);
          acc1[i] = fmaf(m1, tb[i], acc1[i]);
        }
      }
      if (dd + 3 < 32){
        const unsigned short* ap = Eu + (size_t)(d0+dd+3)*8192 + abase;
#pragma unroll
        for (int c = 0; c < 8; c++) A1[c] = *(const uint4*)(ap + c*1024);
      }
    }
    __syncthreads();
#pragma unroll
    for (int r = 0; r < 16; r++){
      int krow = kh*32 + (r&3) + 8*(r>>2) + 4*(lane>>5);
      trb[(th*64 + l31)*66 + krow]      = acc0[r];
      trb[(th*64 + 32 + l31)*66 + krow] = acc1[r];
    }
    __syncthreads();
    float* dst = part + (size_t)rs*T_LEN*KK;
    {
      int t = tid >> 1, kc = (tid & 1)*32;
#pragma unroll
      for (int q = 0; q < 8; q++){
        float4 vv = *(float4*)&trb[t*66 + kc + q*4];
        *(float4*)&dst[(size_t)(t0+t)*KK + kc + q*4] = vv;
      }
    }
  }
  gridbar(&syncb[0]);

  // ===== logBall phase (verbatim R4 k_logBall) =====
  {
    int k = lane;
    float rk = rK[k], lh = Lhalf[k], scl = sclK[k];
    int tbase = bid*32 + w*8;
    float a1[8], a2[8], ssv[8];
#pragma unroll
    for (int tt = 0; tt < 8; tt++){ a1[tt]=0.f; a2[tt]=0.f; ssv[tt]=0.f; }
    for (int dc = 0; dc < DD; dc += 4){
      float c0 = cvecT[(dc+0)*KK + k], c1 = cvecT[(dc+1)*KK + k];
      float c2 = cvecT[(dc+2)*KK + k], c3 = cvecT[(dc+3)*KK + k];
      float e0 = EdiagT[(dc+0)*KK + k], e1 = EdiagT[(dc+1)*KK + k];
      float e2 = EdiagT[(dc+2)*KK + k], e3 = EdiagT[(dc+3)*KK + k];
#pragma unroll
      for (int tt = 0; tt < 8; tt++){
        float4 m4 = *(const float4*)(mu   + (size_t)(tbase+tt)*DD + dc);
        float4 v4 = *(const float4*)(dvar + (size_t)(tbase+tt)*DD + dc);
        a1[tt] = fmaf(m4.x,c0, fmaf(m4.y,c1, fmaf(m4.z,c2, fmaf(m4.w,c3, a1[tt]))));
        a2[tt] = fmaf(fmaxf(v4.x,0.f),e0, fmaf(fmaxf(v4.y,0.f),e1,
                 fmaf(fmaxf(v4.z,0.f),e2, fmaf(fmaxf(v4.w,0.f),e3, a2[tt]))));
        ssv[tt] = fmaf(m4.x,m4.x, fmaf(m4.y,m4.y, fmaf(m4.z,m4.z, fmaf(m4.w,m4.w, ssv[tt]))));
      }
    }
#pragma unroll
    for (int tt = 0; tt < 8; tt++){
      int t = tbase + tt;
      float q = scl*ssv[tt]
              + part[(size_t)0*T_LEN*KK + (size_t)t*KK + k]
              + part[(size_t)1*T_LEN*KK + (size_t)t*KK + k]
              + part[(size_t)2*T_LEN*KK + (size_t)t*KK + k]
              + part[(size_t)3*T_LEN*KK + (size_t)t*KK + k];
      float lb = lh - 0.5f*(q - 2.f*a1[tt] + rk + a2[tt]);
      float m  = wred_max(lb);
      logB[(size_t)t*KK + k] = lb;
      btil[(size_t)t*KK + k] = expf(lb - m);
      if (k == 0) mrow[t] = m;
    }
  }
}

// ---------------- pass1: 8-step chunk operators via bf16 hi/lo MFMA ----------------
__global__ void __launch_bounds__(128, 1) k_pass1(const float* __restrict__ Pm,
     const float* __restrict__ btil, float* __restrict__ G8)
{
  __shared__ float G[64*GP];
  __shared__ float wmax[2][2];
  int tid = threadIdx.x, w = tid >> 6, lane = tid & 63;
  int chunk = blockIdx.x;
  int kb8 = (lane >> 5)*8;
  int n = lane & 31;

  bf16x8 Bhi[4][2], Blo[4][2];
#pragma unroll
  for (int Kb = 0; Kb < 4; Kb++)
#pragma unroll
    for (int J = 0; J < 2; J++){
#pragma unroll
      for (int j = 0; j < 8; j++){
        float p = Pm[(Kb*16 + kb8 + j)*KK + J*32 + n];
        __bf16 h = (__bf16)p;
        Bhi[Kb][J][j] = h;
        Blo[Kb][J][j] = (__bf16)(p - (float)h);
      }
    }
  for (int v = tid; v < 64*64; v += 128){
    int i = v >> 6, j = v & 63;
    G[i*GP + j] = (i == j) ? 1.f : 0.f;
  }
  __syncthreads();

  int m = w*32 + n;
  for (int s = 0; s < 8; s++){
    int t = chunk*8 + s;
    if (t >= 1){
      f32x16 acc0, acc1;
#pragma unroll
      for (int i = 0; i < 16; i++){ acc0[i] = 0.f; acc1[i] = 0.f; }
#pragma unroll
      for (int Kb = 0; Kb < 4; Kb++){
        float4 x0 = *(const float4*)&G[m*GP + Kb*16 + kb8];
        float4 x1 = *(const float4*)&G[m*GP + Kb*16 + kb8 + 4];
        float xv[8] = {x0.x,x0.y,x0.z,x0.w,x1.x,x1.y,x1.z,x1.w};
        bf16x8 ah, al;
#pragma unroll
        for (int j = 0; j < 8; j++){
          __bf16 h = (__bf16)xv[j];
          ah[j] = h;
          al[j] = (__bf16)(xv[j] - (float)h);
        }
        acc0 = __builtin_amdgcn_mfma_f32_32x32x16_bf16(ah, Bhi[Kb][0], acc0, 0,0,0);
        acc0 = __builtin_amdgcn_mfma_f32_32x32x16_bf16(ah, Blo[Kb][0], acc0, 0,0,0);
        acc0 = __builtin_amdgcn_mfma_f32_32x32x16_bf16(al, Bhi[Kb][0], acc0, 0,0,0);
        acc1 = __builtin_amdgcn_mfma_f32_32x32x16_bf16(ah, Bhi[Kb][1], acc1, 0,0,0);
        acc1 = __builtin_amdgcn_mfma_f32_32x32x16_bf16(ah, Blo[Kb][1], acc1, 0,0,0);
        acc1 = __builtin_amdgcn_mfma_f32_32x32x16_bf16(al, Bhi[Kb][1], acc1, 0,0,0);
      }
      float b0 = btil[(size_t)t*KK + n];
      float b1 = btil[(size_t)t*KK + 32 + n];
      float mx = 0.f;
#pragma unroll
      for (int i = 0; i < 16; i++){
        acc0[i] *= b0; acc1[i] *= b1;
        mx = fmaxf(mx, fmaxf(acc0[i], acc1[i]));
      }
      mx = wred_max(mx);
      if (lane == 0) wmax[s&1][w] = mx;
      __syncthreads();
      float inv = 1.f/fmaxf(wmax[s&1][0], wmax[s&1][1]);
#pragma unroll
      for (int r = 0; r < 16; r++){
        int row = w*32 + (r&3) + 8*(r>>2) + 4*(lane>>5);
        G[row*GP + n]      = acc0[r]*inv;
        G[row*GP + 32 + n] = acc1[r]*inv;
      }
    }
  }
  __syncthreads();
  float* dst = G8 + (size_t)chunk*4096;
  for (int v = tid; v < 4096; v += 128) dst[v] = G[(v>>6)*GP + (v&63)];
}

// ---------------- shared device bodies ----------------
__device__ void chain_body(const float* __restrict__ s0, int chain,
    float* __restrict__ X, float (*wmax)[2],
    float* __restrict__ dstLin, int tid, int w, int lane)
{
  int kb8 = (lane >> 5)*8;
  int n = lane & 31;
  int m = w*32 + n;

  for (int v = tid; v < 4096; v += 128) X[(v>>6)*GP + (v&63)] = s0[v];
  __syncthreads();

  for (int j = 1; j < chain; j++){
    const float* Y = s0 + (size_t)j*4096;
    bf16x8 Bh[4][2], Bl[4][2];
#pragma unroll
    for (int Kb = 0; Kb < 4; Kb++)
#pragma unroll
      for (int J = 0; J < 2; J++){
#pragma unroll
        for (int jj = 0; jj < 8; jj++){
          float p = Y[(Kb*16 + kb8 + jj)*64 + J*32 + n];
          __bf16 h = (__bf16)p;
          Bh[Kb][J][jj] = h;
          Bl[Kb][J][jj] = (__bf16)(p - (float)h);
        }
      }
    f32x16 acc0, acc1;
#pragma unroll
    for (int i = 0; i < 16; i++){ acc0[i] = 0.f; acc1[i] = 0.f; }
#pragma unroll
    for (int Kb = 0; Kb < 4; Kb++){
      float4 x0 = *(const float4*)&X[m*GP + Kb*16 + kb8];
      float4 x1 = *(const float4*)&X[m*GP + Kb*16 + kb8 + 4];
      float xv[8] = {x0.x,x0.y,x0.z,x0.w,x1.x,x1.y,x1.z,x1.w};
      bf16x8 ah, al;
#pragma unroll
      for (int q = 0; q < 8; q++){
        __bf16 h = (__bf16)xv[q];
        ah[q] = h;
        al[q] = (__bf16)(xv[q] - (float)h);
      }
      acc0 = __builtin_amdgcn_mfma_f32_32x32x16_bf16(ah, Bh[Kb][0], acc0, 0,0,0);
      acc0 = __builtin_amdgcn_mfma_f32_32x32x16_bf16(ah, Bl[Kb][0], acc0, 0,0,0);
      acc0 = __builtin_amdgcn_mfma_f32_32x32x16_bf16(al, Bh[Kb][0], acc0, 0,0,0);
      acc1 = __builtin_amdgcn_mfma_f32_32x32x16_bf16(ah, Bh[Kb][1], acc1, 0,0,0);
      acc1 = __builtin_amdgcn_mfma_f32_32x32x16_bf16(ah, Bl[Kb][1], acc1, 0,0,0);
      acc1 = __builtin_amdgcn_mfma_f32_32x32x16_bf16(al, Bh[Kb][1], acc1, 0,0,0);
    }
    float mx = 0.f;
#pragma unroll
    for (int i = 0; i < 16; i++) mx = fmaxf(mx, fmaxf(acc0[i], acc1[i]));
    mx = wred_max(mx);
    if (lane == 0) wmax[j&1][w] = mx;
    __syncthreads();
    float inv = 1.f/fmaxf(wmax[j&1][0], wmax[j&1][1]);
#pragma unroll
    for (int r = 0; r < 16; r++){
      int row = w*32 + (r&3) + 8*(r>>2) + 4*(lane>>5);
      X[row*GP + n]      = acc0[r]*inv;
      X[row*GP + 32 + n] = acc1[r]*inv;
    }
    __syncthreads();
  }
  for (int v = tid; v < 4096; v += 128) dstLin[v] = X[(v>>6)*GP + (v&63)];
}

__device__ void mat_combine(const float* __restrict__ A, const float* __restrict__ B,
    float* __restrict__ out, float* __restrict__ outT,
    float* __restrict__ X, float* __restrict__ wmax, int tid, int w, int lane)
{
  int kb8 = (lane >> 5)*8;
  int n = lane & 31;
  int m = w*32 + n;
  for (int v = tid; v < 4096; v += 128) X[(v>>6)*GP + (v&63)] = A[v];
  bf16x8 Bh[4][2], Bl[4][2];
#pragma unroll
  for (int Kb = 0; Kb < 4; Kb++)
#pragma unroll
    for (int J = 0; J < 2; J++){
#pragma unroll
      for (int jj = 0; jj < 8; jj++){
        float p = B[(Kb*16 + kb8 + jj)*64 + J*32 + n];
        __bf16 h = (__bf16)p;
        Bh[Kb][J][jj] = h;
        Bl[Kb][J][jj] = (__bf16)(p - (float)h);
      }
    }
  __syncthreads();
  f32x16 acc0, acc1;
#pragma unroll
  for (int i = 0; i < 16; i++){ acc0[i] = 0.f; acc1[i] = 0.f; }
#pragma unroll
  for (int Kb = 0; Kb < 4; Kb++){
    float4 x0 = *(const float4*)&X[m*GP + Kb*16 + kb8];
    float4 x1 = *(const float4*)&X[m*GP + Kb*16 + kb8 + 4];
    float xv[8] = {x0.x,x0.y,x0.z,x0.w,x1.x,x1.y,x1.z,x1.w};
    bf16x8 ah, al;
#pragma unroll
    for (int q = 0; q < 8; q++){
      __bf16 h = (__bf16)xv[q];
      ah[q] = h;
      al[q] = (__bf16)(xv[q] - (float)h);
    }
    acc0 = __builtin_amdgcn_mfma_f32_32x32x16_bf16(ah, Bh[Kb][0], acc0, 0,0,0);
    acc0 = __builtin_amdgcn_mfma_f32_32x32x16_bf16(ah, Bl[Kb][0], acc0, 0,0,0);
    acc0 = __builtin_amdgcn_mfma_f32_32x32x16_bf16(al, Bh[Kb][0], acc0, 0,0,0);
    acc1 = __builtin_amdgcn_mfma_f32_32x32x16_bf16(ah, Bh[Kb][1], acc1, 0,0,0);
    acc1 = __builtin_amdgcn_mfma_f32_32x32x16_bf16(ah, Bl[Kb][1], acc1, 0,0,0);
    acc1 = __builtin_amdgcn_mfma_f32_32x32x16_bf16(al, Bh[Kb][1], acc1, 0,0,0);
  }
  float mx = 0.f;
#pragma unroll
  for (int i = 0; i < 16; i++) mx = fmaxf(mx, fmaxf(acc0[i], acc1[i]));
  mx = wred_max(mx);
  if (lane == 0) wmax[w] = mx;
  __syncthreads();
  float inv = 1.f/fmaxf(wmax[0], wmax[1]);
#pragma unroll
  for (int r = 0; r < 16; r++){
    int row = w*32 + (r&3) + 8*(r>>2) + 4*(lane>>5);
    out[row*64 + n]      = acc0[r]*inv;
    out[row*64 + 32 + n] = acc1[r]*inv;
  }
  if (outT){
    __syncthreads();
#pragma unroll
    for (int r = 0; r < 16; r++){
      int row = w*32 + (r&3) + 8*(r>>2) + 4*(lane>>5);
      X[row*GP + n]      = acc0[r]*inv;
      X[row*GP + 32 + n] = acc1[r]*inv;
    }
    __syncthreads();
    for (int v = tid; v < 4096; v += 128) outT[v] = X[(v&63)*GP + (v>>6)];
  }
}

__device__ void mat_copy(const float* __restrict__ A, float* __restrict__ out,
    float* __restrict__ outT, float* __restrict__ X, int tid)
{
  if (!outT){
    for (int v = tid; v < 4096; v += 128) out[v] = A[v];
  } else {
    for (int v = tid; v < 4096; v += 128){
      float vv = A[v];
      out[v] = vv;
      X[(v>>6)*GP + (v&63)] = vv;
    }
    __syncthreads();
    for (int v = tid; v < 4096; v += 128) outT[v] = X[(v&63)*GP + (v>>6)];
  }
}

// ---------------- k_back: chain8 -> KSx7 (PA/SB on separate block halves) -> pass3 ----------------
__global__ void __launch_bounds__(128, 1) k_back(
    float* G8, float* __restrict__ H64,
    const float* __restrict__ Pm, const float* __restrict__ PTm,
    const float* __restrict__ logB, const float* __restrict__ mrow,
    const float* __restrict__ btil, const float* __restrict__ log_pi,
    float* __restrict__ ah, float* __restrict__ bh, float* __restrict__ llp,
    int* __restrict__ syncb)
{
  __shared__ float X[64*GP];
  __shared__ float wmaxc[2][2];
  __shared__ float wmax1[2];
  int tid = threadIdx.x, bid = blockIdx.x;
  int w = tid >> 6, lane = tid & 63;

  // ===== chain8: blocks 0..127 =====
  if (bid < 128)
    chain_body(G8 + (size_t)bid*8*4096, 8, X, wmaxc, H64 + (size_t)bid*4096, tid, w, lane);
  gridbar(&syncb[1]);

  // ===== 7 KS rounds: blocks 0..127 = PA side, 128..255 = SB side =====
  const size_t M = (size_t)128*4096;
  float* PAbuf[2] = {G8, G8 + M};
  float* SBbuf[2] = {G8 + 2*M, G8 + 3*M};
  float* SBT = G8 + 4*M;
  const float* PAin = H64; const float* SBin = H64;
  int cur = 1;
  int side = bid >> 7, c = bid & 127;
  for (int r = 0; r < 7; r++){
    int s = 1 << r;
    int wrT = (r == 6);
    if (side == 0){
      if (c >= s)
        mat_combine(PAin + (size_t)(c-s)*4096, PAin + (size_t)c*4096,
                    PAbuf[cur] + (size_t)c*4096, nullptr, X, wmax1, tid, w, lane);
      else
        mat_copy(PAin + (size_t)c*4096, PAbuf[cur] + (size_t)c*4096, nullptr, X, tid);
    } else {
      float* t = wrT ? (SBT + (size_t)c*4096) : nullptr;
      if (c + s <= 127)
        mat_combine(SBin + (size_t)c*4096, SBin + (size_t)(c+s)*4096,
                    SBbuf[cur] + (size_t)c*4096, t, X, wmax1, tid, w, lane);
      else
        mat_copy(SBin + (size_t)c*4096, SBbuf[cur] + (size_t)c*4096, t, X, tid);
    }
    gridbar(&syncb[2 + r]);
    PAin = PAbuf[cur]; SBin = SBbuf[cur]; cur ^= 1;
  }
  const float* PAfin = PAin;

  // ===== pass3: wave0 of each block handles task bid (alpha bid<128, beta bid>=128) =====
  if (tid >= 64) return;
  {
    int lane0 = tid;
    if (bid < 128){
      int cc = bid;
      float Preg[64];
#pragma unroll
      for (int i = 0; i < 64; i++) Preg[i] = Pm[i*64 + lane0];
      float a; float llacc = 0.f;
      int tstart;
      float x0v = log_pi[lane0] + logB[lane0];
      float mm0 = wred_max(x0v);
      float e0 = expf(x0v - mm0);
      float ss0 = wred_sum(e0);
      if (cc == 0){
        a = e0/ss0;
        llacc = mm0 + logf(ss0);
        ah[lane0] = a;
        tstart = 1;
      } else {
        float a0 = e0/ss0;
        const float* H = PAfin + (size_t)(cc-1)*4096;
        float Hr[64];
#pragma unroll
        for (int i = 0; i < 64; i++) Hr[i] = H[i*64 + lane0];
        float p0 = 0.f, p1 = 0.f, p2 = 0.f, p3 = 0.f;
#pragma unroll
        for (int i = 0; i < 16; i++){
          p0 = fmaf(__shfl(a0, i,      64), Hr[i],      p0);
          p1 = fmaf(__shfl(a0, i + 16, 64), Hr[i + 16], p1);
          p2 = fmaf(__shfl(a0, i + 32, 64), Hr[i + 32], p2);
          p3 = fmaf(__shfl(a0, i + 48, 64), Hr[i + 48], p3);
        }
        a = (p0 + p1) + (p2 + p3);
        a /= wred_sum(a);
        tstart = cc*64;
      }
      int tend = cc*64 + 64;
      float bt = btil[(size_t)tstart*KK + lane0];
      for (int t = tstart; t < tend; t++){
        float btn = 0.f;
        if (t + 1 < tend) btn = btil[(size_t)(t+1)*KK + lane0];
        float mr = mrow[t];
        float p0 = 0.f, p1 = 0.f, p2 = 0.f, p3 = 0.f;
#pragma unroll
        for (int i = 0; i < 16; i++){
          p0 = fmaf(__shfl(a, i,      64), Preg[i],      p0);
          p1 = fmaf(__shfl(a, i + 16, 64), Preg[i + 16], p1);
          p2 = fmaf(__shfl(a, i + 32, 64), Preg[i + 32], p2);
          p3 = fmaf(__shfl(a, i + 48, 64), Preg[i + 48], p3);
        }
        float pred = (p0 + p1) + (p2 + p3);
        a = pred * bt;
        if (((t - tstart) & 3) == 3 || t == tend - 1){
          float s = wred_sum(a);
          a = a / s;
          llacc += logf(s);
        }
        llacc += mr;
        ah[(size_t)t*KK + lane0] = a;
        bt = btn;
      }
      if (lane0 == 0) llp[cc] = llacc;
    } else {
      int cc = bid - 128;
      float PTreg[64];
#pragma unroll
      for (int j = 0; j < 64; j++) PTreg[j] = PTm[j*64 + lane0];
      float b, lb;
      if (cc == 127){
        b = 1.f; lb = 0.f;
      } else {
        const float* H = SBT + (size_t)(cc+1)*4096;
        float s0 = 0.f, s1 = 0.f, s2 = 0.f, s3 = 0.f;
#pragma unroll
        for (int i = 0; i < 16; i++){
          s0 += H[(i     )*64 + lane0];
          s1 += H[(i + 16)*64 + lane0];
          s2 += H[(i + 32)*64 + lane0];
          s3 += H[(i + 48)*64 + lane0];
        }
        float s = (s0 + s1) + (s2 + s3);
        float mmb = wred_max(s);
        b = s/mmb;
        lb = logf(b);
      }
      int t1 = cc*64 + 63;
      bh[(size_t)t1*KK + lane0] = b;
      float lgb = logB[(size_t)t1*KK + lane0];
      float mrn = mrow[t1];
      for (int t = t1 - 1; t >= cc*64; t--){
        float lgbn = 0.f, mrnn = 0.f;
        if (t > cc*64){
          lgbn = logB[(size_t)t*KK + lane0];
          mrnn = mrow[t];
        }
        float lv = (lgb - mrn) + lb;
        float vm = wred_max(lv);
        float vv = expf(lv - vm);
        float q0 = 0.f, q1r = 0.f, q2 = 0.f, q3 = 0.f;
#pragma unroll
        for (int j = 0; j < 16; j++){
          q0  = fmaf(PTreg[j],      __shfl(vv, j,      64), q0);
          q1r = fmaf(PTreg[j + 16], __shfl(vv, j + 16, 64), q1r);
          q2  = fmaf(PTreg[j + 32], __shfl(vv, j + 32, 64), q2);
          q3  = fmaf(PTreg[j + 48], __shfl(vv, j + 48, 64), q3);
        }
        b = (q0 + q1r) + (q2 + q3);
        lb = logf(b);
        bh[(size_t)t*KK + lane0] = b;
        lgb = lgbn; mrn = mrnn;
      }
    }
  }
}

// ---------------- merged outputs: rhat + xihat + ll ----------------
__global__ void __launch_bounds__(256) k_outs(const float* __restrict__ ah,
     const float* __restrict__ bh, const float* __restrict__ ElogA,
     const float* __restrict__ logB, const float* __restrict__ llp,
     float* __restrict__ out_rhat, float* __restrict__ out_xi, float* __restrict__ out_ll)
{
  __shared__ float la[64], wc[64];
  __shared__ float redm[4], reds[4];
  int tid = threadIdx.x;
  int b = blockIdx.x;
  if (tid < 64) la[tid] = logf(ah[(size_t)b*KK + tid]);
  else if (tid < 128 && b < T_LEN-1){
    int j = tid - 64;
    wc[j] = logB[(size_t)(b+1)*KK + j] + logf(bh[(size_t)(b+1)*KK + j]);
  }
  __syncthreads();
  if (tid < 64){
    float s = la[tid] + logf(bh[(size_t)b*KK + tid]);
    float m = wred_max(s);
    float p = (m < -3.0e37f) ? 1.f : expf(s - m);
    float ss = wred_sum(p);
    out_rhat[(size_t)b*KK + tid] = p/ss;
  }
  if (b == T_LEN-1){
    if (tid >= 64 && tid < 128){
      int i = tid - 64;
      float v = llp[i] + llp[i + 64];
      v = wred_sum(v);
      if (i == 0) out_ll[0] = v;
    }
    return;
  }
  int lane = tid & 63, w = tid >> 6;
  int j0 = (lane & 15) << 2;
  int ibase = w*16 + (lane >> 4)*4;
  float4 wc4 = *(float4*)&wc[j0];
  float sv[16];
  float mx = -3.0e38f;
#pragma unroll
  for (int ii = 0; ii < 4; ii++){
    float lai = la[ibase + ii];
    float4 e4 = *(const float4*)&ElogA[(ibase+ii)*KK + j0];
    float s0 = lai + e4.x + wc4.x;
    float s1 = lai + e4.y + wc4.y;
    float s2 = lai + e4.z + wc4.z;
    float s3 = lai + e4.w + wc4.w;
    sv[ii*4+0]=s0; sv[ii*4+1]=s1; sv[ii*4+2]=s2; sv[ii*4+3]=s3;
    mx = fmaxf(fmaxf(fmaxf(mx, s0), fmaxf(s1, s2)), s3);
  }
  float mxw = wred_max(mx);
  if (lane == 0) redm[w] = mxw;
  __syncthreads();
  float m = fmaxf(fmaxf(redm[0], redm[1]), fmaxf(redm[2], redm[3]));
  bool degen = !(m > -3.0e37f);
  float pv[16]; float ps = 0.f;
#pragma unroll
  for (int n = 0; n < 16; n++){
    float p = degen ? 1.f : expf(sv[n] - m);
    pv[n] = p; ps += p;
  }
  float psw = wred_sum(ps);
  if (lane == 0) reds[w] = psw;
  __syncthreads();
  float inv = 1.f/(reds[0] + reds[1] + reds[2] + reds[3]);
  float* dst = out_xi + (size_t)b*4096;
#pragma unroll
  for (int ii = 0; ii < 4; ii++){
    float4 o;
    o.x = pv[ii*4+0]*inv; o.y = pv[ii*4+1]*inv;
    o.z = pv[ii*4+2]*inv; o.w = pv[ii*4+3]*inv;
    *(float4*)&dst[(ibase+ii)*KK + j0] = o;
  }
}

extern "C" void kernel_launch(void* const* d_in, const int* in_sizes, int n_in,
                              void* d_out, int out_size, void* d_ws, size_t ws_size,
                              hipStream_t stream)
{
  const float* mu    = (const float*)d_in[0];
  const float* dvar  = (const float*)d_in[1];
  const float* niwmu = (const float*)d_in[2];
  const float* Psi   = (const float*)d_in[3];
  const float* nu    = (const float*)d_in[4];
  const float* phi   = (const float*)d_in[5];
  const float* lpi   = (const float*)d_in[6];
  float* out = (float*)d_out;
  float* ws  = (float*)d_ws;

  size_t o = 0;
  float* EbfF   = ws + o; o += (size_t)DD*DD*KK/2;
  float* EdiagT = ws + o; o += (size_t)DD*KK;
  float* cvecT  = ws + o; o += (size_t)DD*KK;
  float* rK     = ws + o; o += KK;
  float* Lhalf  = ws + o; o += KK;
  float* sclK   = ws + o; o += KK;
  float* ElogA  = ws + o; o += KK*KK;
  float* P      = ws + o; o += KK*KK;
  float* PT     = ws + o; o += KK*KK;
  float* logB   = ws + o; o += (size_t)T_LEN*KK;
  float* mrowp  = ws + o; o += T_LEN;
  float* btil   = ws + o; o += (size_t)T_LEN*KK;
  float* G8     = ws + o; o += (size_t)1024*4096;
  float* H64    = ws + o; o += (size_t)128*4096;
  float* llp    = ws + o; o += 128;
  float* ah     = ws + o; o += (size_t)T_LEN*KK;
  float* bh     = ws + o; o += (size_t)T_LEN*KK;
  int*   syncb  = (int*)(ws + o); o += 16;
  if (ws_size < o*sizeof(float)) return;

  __bf16* Ebf = (__bf16*)EbfF;
  float*  part = G8;   // alias: consumed by logBall phase before k_pass1 writes G8

  hipFuncSetAttribute((const void*)k_neumann, hipFuncAttributeMaxDynamicSharedMemorySize, 2*DD*RS*4);

  k_neumann<<<64, 256, 2*DD*RS*4, stream>>>(Psi, niwmu, nu, phi, Ebf, EdiagT, cvecT, rK, Lhalf, sclK, ElogA, P, PT, syncb);
  k_front<<<256, 256, 0, stream>>>(mu, dvar, Ebf, cvecT, EdiagT, rK, Lhalf, sclK, part, logB, mrowp, btil, syncb);
  k_pass1<<<1024, 128, 0, stream>>>(P, btil, G8);
  k_back<<<256, 128, 0, stream>>>(G8, H64, P, PT, logB, mrowp, btil, lpi, ah, bh, llp, syncb);
  k_outs<<<T_LEN, 256, 0, stream>>>(ah, bh, ElogA, logB, llp, out, out + (size_t)T_LEN*KK,
                                    out + (size_t)T_LEN*KK + (size_t)(T_LEN-1)*KK*KK);
}

// Round 7
// 425.711 us; speedup vs baseline: 1.6668x; 1.2718x over previous
//
#include <hip/hip_runtime.h>
#include <math.h>

#define T_LEN 8192
#define KK 64
#define DD 128
#define RS 132
#define GP 68

typedef __bf16  bf16x4 __attribute__((ext_vector_type(4)));
typedef __bf16  bf16x8 __attribute__((ext_vector_type(8)));
typedef float  f32x16 __attribute__((ext_vector_type(16)));

__device__ __forceinline__ float wred_max(float v){
#pragma unroll
  for (int m = 1; m < 64; m <<= 1) v = fmaxf(v, __shfl_xor(v, m, 64));
  return v;
}
__device__ __forceinline__ float wred_sum(float v){
#pragma unroll
  for (int m = 1; m < 64; m <<= 1) v += __shfl_xor(v, m, 64);
  return v;
}
__device__ __forceinline__ float digamma_f(float x){
  float r = 0.f;
  while (x < 6.f){ r -= 1.f/x; x += 1.f; }
  float ix = 1.f/x, ix2 = ix*ix;
  return r + logf(x) - 0.5f*ix - ix2*(0.0833333333f - ix2*(0.0083333333f - ix2*0.0039682540f));
}

// ---------------- Neumann inverse + logdet + ElogA/P/PT ----------------
__global__ void __launch_bounds__(256, 1) k_neumann(
    const float* __restrict__ Psi, const float* __restrict__ niw_mu,
    const float* __restrict__ nu_, const float* __restrict__ phi,
    __bf16* __restrict__ Ebf, float* __restrict__ EdiagT,
    float* __restrict__ cvecT, float* __restrict__ rK, float* __restrict__ Lhalf,
    float* __restrict__ sclK,
    float* __restrict__ ElogA, float* __restrict__ P, float* __restrict__ PT)
{
  extern __shared__ float lds[];
  float* Rl = lds;            // [DD][RS]
  float* Pb = lds + DD*RS;    // [DD][RS]
  __shared__ float red[256];
  __shared__ float msh[DD];
  int k = blockIdx.x, tid = threadIdx.x;
  const float* A = Psi + (size_t)k*DD*DD;

  if (tid < 64){
    float ph = phi[k*KK + tid];
    float s  = wred_sum(ph);
    float e  = digamma_f(ph) - digamma_f(s);
    ElogA[k*KK + tid] = e;
    float p = expf(e);
    P [k*KK + tid] = p;
    PT[tid*KK + k] = p;
  }

  float tl = 0.f;
  for (int d = tid; d < DD; d += 256) tl += A[d*DD + d];
  red[tid] = tl; __syncthreads();
  for (int off = 128; off > 0; off >>= 1){ if (tid < off) red[tid] += red[tid+off]; __syncthreads(); }
  float c = red[0] / (float)DD;
  __syncthreads();

  float trpow = 0.f;
  for (int idx = tid; idx < DD*DD; idx += 256){
    int d = idx >> 7, e = idx & 127;
    float v = ((d == e) ? 1.f : 0.f) - A[idx]/c;
    Rl[d*RS + e] = v;
    if (d == e) trpow += v;
  }
  __syncthreads();

  int tr = tid >> 4, tc = tid & 15;
  int r0 = tr*8, c0 = tc*8;
  float S[8][8];
#pragma unroll
  for (int i = 0; i < 8; i++)
#pragma unroll
    for (int j = 0; j < 8; j++){
      float v = Rl[(r0+i)*RS + c0+j];
      if (r0+i == c0+j) v += 1.f;
      S[i][j] = v;
    }

  {
    float Cc[8][8];
#pragma unroll
    for (int i = 0; i < 8; i++)
#pragma unroll
      for (int j = 0; j < 8; j++) Cc[i][j] = 0.f;
    for (int l = 0; l < DD; l += 4){
      float af[4][8], bf[4][8];
#pragma unroll
      for (int q = 0; q < 4; q++){
        float4 x0 = *(const float4*)&Rl[(l+q)*RS + r0];
        float4 x1 = *(const float4*)&Rl[(l+q)*RS + r0 + 4];
        af[q][0]=x0.x; af[q][1]=x0.y; af[q][2]=x0.z; af[q][3]=x0.w;
        af[q][4]=x1.x; af[q][5]=x1.y; af[q][6]=x1.z; af[q][7]=x1.w;
        float4 y0 = *(const float4*)&Rl[(l+q)*RS + c0];
        float4 y1 = *(const float4*)&Rl[(l+q)*RS + c0 + 4];
        bf[q][0]=y0.x; bf[q][1]=y0.y; bf[q][2]=y0.z; bf[q][3]=y0.w;
        bf[q][4]=y1.x; bf[q][5]=y1.y; bf[q][6]=y1.z; bf[q][7]=y1.w;
      }
#pragma unroll
      for (int q = 0; q < 4; q++)
#pragma unroll
        for (int i = 0; i < 8; i++)
#pragma unroll
          for (int j = 0; j < 8; j++)
            Cc[i][j] = fmaf(af[q][i], bf[q][j], Cc[i][j]);
    }
#pragma unroll
    for (int i = 0; i < 8; i++)
#pragma unroll
      for (int j = 0; j < 8; j++) S[i][j] += Cc[i][j];
    if (tr == tc){
#pragma unroll
      for (int i = 0; i < 8; i++) trpow += Cc[i][i]*0.5f;
    }
  }

  red[tid] = trpow; __syncthreads();
  for (int off = 128; off > 0; off >>= 1){ if (tid < off) red[tid] += red[tid+off]; __syncthreads(); }
  float trsum = red[0];
  __syncthreads();

  float nu = nu_[k];
  float dl = 0.f;
  for (int i = tid; i < DD; i += 256) dl += digamma_f((nu - (float)i)*0.5f);
  red[tid] = dl; __syncthreads();
  for (int off = 128; off > 0; off >>= 1){ if (tid < off) red[tid] += red[tid+off]; __syncthreads(); }
  if (tid == 0){
    float logdetPsi = (float)DD*logf(c) - trsum;
    float Elogdet = red[0] + (float)DD*0.69314718056f - logdetPsi;
    Lhalf[k] = 0.5f*Elogdet - 0.5f*(float)DD*1.83787706641f;
    sclK[k]  = nu / c;
  }
  __syncthreads();

  float scl = nu / c;
#pragma unroll
  for (int i = 0; i < 8; i++)
#pragma unroll
    for (int j = 0; j < 8; j++){
      float sv = S[i][j];
      bool dg = (r0+i == c0+j);
      if (dg) EdiagT[(r0+i)*KK + k] = scl*sv;
      float et = scl*(sv - (dg ? 1.f : 0.f));
      int r = (r0+i)*DD + (c0+j);
      Ebf[(size_t)(r>>4)*1024 + k*16 + (r&15)] = (__bf16)et;
    }
#pragma unroll
  for (int i = 0; i < 8; i++){
    float4 w0, w1;
    w0.x=S[i][0]; w0.y=S[i][1]; w0.z=S[i][2]; w0.w=S[i][3];
    w1.x=S[i][4]; w1.y=S[i][5]; w1.z=S[i][6]; w1.w=S[i][7];
    *(float4*)&Pb[(r0+i)*RS + c0]     = w0;
    *(float4*)&Pb[(r0+i)*RS + c0 + 4] = w1;
  }
  for (int d = tid; d < DD; d += 256) msh[d] = niw_mu[k*DD + d];
  __syncthreads();
  float cv = 0.f;
  if (tid < DD){
    float acc = 0.f;
    for (int e = 0; e < DD; e++) acc += Pb[tid*RS + e]*msh[e];
    cv = scl*acc;
    cvecT[tid*KK + k] = cv;
  }
  red[tid] = (tid < DD) ? msh[tid]*cv : 0.f; __syncthreads();
  for (int off = 128; off > 0; off >>= 1){ if (tid < off) red[tid] += red[tid+off]; __syncthreads(); }
  if (tid == 0) rK[k] = red[0];
}

// ---------------- residual quad GEMM: d-grouped, E streamed L2->regs ----------------
__global__ void __launch_bounds__(256, 1) k_q1(const float* __restrict__ mu,
      const __bf16* __restrict__ Ebf, float* __restrict__ part)
{
  __shared__ float muF[32*132];
  __shared__ float trb[128*66];
  int b = blockIdx.x;
  int rs = b & 3, tseg = b >> 2;
  int t0 = tseg*128, d0 = rs*32;
  int tid = threadIdx.x;
  int w = tid >> 6, lane = tid & 63;
  int kh = w & 1, th = w >> 1;
  int l31 = lane & 31;
  int k0 = (lane >> 5)*8;

  for (int v = tid; v < 128*32; v += 256){
    int t = v >> 5, d = v & 31;
    muF[d*132 + t] = mu[(size_t)(t0+t)*DD + d0 + d];
  }

  bf16x8 Bf0[8], Bf1[8];
#pragma unroll
  for (int c = 0; c < 8; c++){
    int tc0 = t0 + th*64 + l31;
    int tc1 = tc0 + 32;
    float4 x0 = *(const float4*)&mu[(size_t)tc0*DD + c*16 + k0];
    float4 x1 = *(const float4*)&mu[(size_t)tc0*DD + c*16 + k0 + 4];
    bf16x8 hv;
    hv[0]=(__bf16)x0.x; hv[1]=(__bf16)x0.y; hv[2]=(__bf16)x0.z; hv[3]=(__bf16)x0.w;
    hv[4]=(__bf16)x1.x; hv[5]=(__bf16)x1.y; hv[6]=(__bf16)x1.z; hv[7]=(__bf16)x1.w;
    Bf0[c] = hv;
    float4 y0 = *(const float4*)&mu[(size_t)tc1*DD + c*16 + k0];
    float4 y1 = *(const float4*)&mu[(size_t)tc1*DD + c*16 + k0 + 4];
    bf16x8 gv;
    gv[0]=(__bf16)y0.x; gv[1]=(__bf16)y0.y; gv[2]=(__bf16)y0.z; gv[3]=(__bf16)y0.w;
    gv[4]=(__bf16)y1.x; gv[5]=(__bf16)y1.y; gv[6]=(__bf16)y1.z; gv[7]=(__bf16)y1.w;
    Bf1[c] = gv;
  }
  __syncthreads();

  const unsigned short* __restrict__ Eu = (const unsigned short*)Ebf;
  size_t abase = (size_t)(kh*32 + l31)*16 + k0;

  f32x16 acc0, acc1;
#pragma unroll
  for (int i = 0; i < 16; i++){ acc0[i]=0.f; acc1[i]=0.f; }

  uint4 A0[8], A1[8];
  {
    const unsigned short* ap = Eu + (size_t)d0*8192 + abase;
#pragma unroll
    for (int c = 0; c < 8; c++) A0[c] = *(const uint4*)(ap + c*1024);
#pragma unroll
    for (int c = 0; c < 8; c++) A1[c] = *(const uint4*)(ap + 8192 + c*1024);
  }

  for (int dd = 0; dd < 32; dd += 2){
    {
      f32x16 ta, tb;
#pragma unroll
      for (int i = 0; i < 16; i++){ ta[i]=0.f; tb[i]=0.f; }
#pragma unroll
      for (int c = 0; c < 8; c++){
        bf16x8 av = *(bf16x8*)&A0[c];
        ta = __builtin_amdgcn_mfma_f32_32x32x16_bf16(av, Bf0[c], ta, 0, 0, 0);
        tb = __builtin_amdgcn_mfma_f32_32x32x16_bf16(av, Bf1[c], tb, 0, 0, 0);
      }
      float m0 = muF[dd*132 + th*64 + l31];
      float m1 = muF[dd*132 + th*64 + 32 + l31];
#pragma unroll
      for (int i = 0; i < 16; i++){
        acc0[i] = fmaf(m0, ta[i], acc0[i]);
        acc1[i] = fmaf(m1, tb[i], acc1[i]);
      }
    }
    if (dd + 2 < 32){
      const unsigned short* ap = Eu + (size_t)(d0+dd+2)*8192 + abase;
#pragma unroll
      for (int c = 0; c < 8; c++) A0[c] = *(const uint4*)(ap + c*1024);
    }
    {
      f32x16 ta, tb;
#pragma unroll
      for (int i = 0; i < 16; i++){ ta[i]=0.f; tb[i]=0.f; }
#pragma unroll
      for (int c = 0; c < 8; c++){
        bf16x8 av = *(bf16x8*)&A1[c];
        ta = __builtin_amdgcn_mfma_f32_32x32x16_bf16(av, Bf0[c], ta, 0, 0, 0);
        tb = __builtin_amdgcn_mfma_f32_32x32x16_bf16(av, Bf1[c], tb, 0, 0, 0);
      }
      float m0 = muF[(dd+1)*132 + th*64 + l31];
      float m1 = muF[(dd+1)*132 + th*64 + 32 + l31];
#pragma unroll
      for (int i = 0; i < 16; i++){
        acc0[i] = fmaf(m0, ta[i], acc0[i]);
        acc1[i] = fmaf(m1, tb[i], acc1[i]);
      }
    }
    if (dd + 3 < 32){
      const unsigned short* ap = Eu + (size_t)(d0+dd+3)*8192 + abase;
#pragma unroll
      for (int c = 0; c < 8; c++) A1[c] = *(const uint4*)(ap + c*1024);
    }
  }

  __syncthreads();
#pragma unroll
  for (int r = 0; r < 16; r++){
    int krow = kh*32 + (r&3) + 8*(r>>2) + 4*(lane>>5);
    trb[(th*64 + l31)*66 + krow]      = acc0[r];
    trb[(th*64 + 32 + l31)*66 + krow] = acc1[r];
  }
  __syncthreads();
  float* dst = part + (size_t)rs*T_LEN*KK;
  {
    int t = tid >> 1, kc = (tid & 1)*32;
#pragma unroll
    for (int q = 0; q < 8; q++){
      float4 vv = *(float4*)&trb[t*66 + kc + q*4];
      *(float4*)&dst[(size_t)(t0+t)*KK + kc + q*4] = vv;
    }
  }
}

// ---------------- finalize logB ----------------
__global__ void __launch_bounds__(256) k_logBall(
    const float* __restrict__ part, const float* __restrict__ mu, const float* __restrict__ dvar,
    const float* __restrict__ cvecT, const float* __restrict__ EdiagT,
    const float* __restrict__ rK, const float* __restrict__ Lhalf, const float* __restrict__ sclK,
    float* __restrict__ logB, float* __restrict__ mrow, float* __restrict__ btil)
{
  int tid = threadIdx.x; int k = tid & 63; int w = tid >> 6;
  float rk = rK[k], lh = Lhalf[k], scl = sclK[k];
  int tbase = blockIdx.x*32 + w*8;
  float a1[8], a2[8], ssv[8];
#pragma unroll
  for (int tt = 0; tt < 8; tt++){ a1[tt]=0.f; a2[tt]=0.f; ssv[tt]=0.f; }
  for (int dc = 0; dc < DD; dc += 4){
    float c0 = cvecT[(dc+0)*KK + k], c1 = cvecT[(dc+1)*KK + k];
    float c2 = cvecT[(dc+2)*KK + k], c3 = cvecT[(dc+3)*KK + k];
    float e0 = EdiagT[(dc+0)*KK + k], e1 = EdiagT[(dc+1)*KK + k];
    float e2 = EdiagT[(dc+2)*KK + k], e3 = EdiagT[(dc+3)*KK + k];
#pragma unroll
    for (int tt = 0; tt < 8; tt++){
      float4 m4 = *(const float4*)(mu   + (size_t)(tbase+tt)*DD + dc);
      float4 v4 = *(const float4*)(dvar + (size_t)(tbase+tt)*DD + dc);
      a1[tt] = fmaf(m4.x,c0, fmaf(m4.y,c1, fmaf(m4.z,c2, fmaf(m4.w,c3, a1[tt]))));
      a2[tt] = fmaf(fmaxf(v4.x,0.f),e0, fmaf(fmaxf(v4.y,0.f),e1,
               fmaf(fmaxf(v4.z,0.f),e2, fmaf(fmaxf(v4.w,0.f),e3, a2[tt]))));
      ssv[tt] = fmaf(m4.x,m4.x, fmaf(m4.y,m4.y, fmaf(m4.z,m4.z, fmaf(m4.w,m4.w, ssv[tt]))));
    }
  }
#pragma unroll
  for (int tt = 0; tt < 8; tt++){
    int t = tbase + tt;
    float q = scl*ssv[tt]
            + part[(size_t)0*T_LEN*KK + (size_t)t*KK + k]
            + part[(size_t)1*T_LEN*KK + (size_t)t*KK + k]
            + part[(size_t)2*T_LEN*KK + (size_t)t*KK + k]
            + part[(size_t)3*T_LEN*KK + (size_t)t*KK + k];
    float lb = lh - 0.5f*(q - 2.f*a1[tt] + rk + a2[tt]);
    float m  = wred_max(lb);
    logB[(size_t)t*KK + k] = lb;
    btil[(size_t)t*KK + k] = expf(lb - m);
    if (k == 0) mrow[t] = m;
  }
}

// ---------------- pass32: 32-step chunk operators (replaces pass1 + chain8, no G8) ----------------
__global__ void __launch_bounds__(128, 1) k_pass32(const float* __restrict__ Pm,
     const float* __restrict__ btil, float* __restrict__ H32, float* __restrict__ H32T)
{
  __shared__ float G[64*GP];
  __shared__ float wmax[2][2];
  int tid = threadIdx.x, w = tid >> 6, lane = tid & 63;
  int chunk = blockIdx.x;     // 256 chunks x 32 steps
  int kb8 = (lane >> 5)*8;
  int n = lane & 31;

  bf16x8 Bhi[4][2], Blo[4][2];
#pragma unroll
  for (int Kb = 0; Kb < 4; Kb++)
#pragma unroll
    for (int J = 0; J < 2; J++){
#pragma unroll
      for (int j = 0; j < 8; j++){
        float p = Pm[(Kb*16 + kb8 + j)*KK + J*32 + n];
        __bf16 h = (__bf16)p;
        Bhi[Kb][J][j] = h;
        Blo[Kb][J][j] = (__bf16)(p - (float)h);
      }
    }
  for (int v = tid; v < 64*64; v += 128){
    int i = v >> 6, j = v & 63;
    G[i*GP + j] = (i == j) ? 1.f : 0.f;
  }
  __syncthreads();

  int m = w*32 + n;
  for (int s = 0; s < 32; s++){
    int t = chunk*32 + s;
    if (t >= 1){
      f32x16 acc0, acc1;
#pragma unroll
      for (int i = 0; i < 16; i++){ acc0[i] = 0.f; acc1[i] = 0.f; }
#pragma unroll
      for (int Kb = 0; Kb < 4; Kb++){
        float4 x0 = *(const float4*)&G[m*GP + Kb*16 + kb8];
        float4 x1 = *(const float4*)&G[m*GP + Kb*16 + kb8 + 4];
        float xv[8] = {x0.x,x0.y,x0.z,x0.w,x1.x,x1.y,x1.z,x1.w};
        bf16x8 ah, al;
#pragma unroll
        for (int j = 0; j < 8; j++){
          __bf16 h = (__bf16)xv[j];
          ah[j] = h;
          al[j] = (__bf16)(xv[j] - (float)h);
        }
        acc0 = __builtin_amdgcn_mfma_f32_32x32x16_bf16(ah, Bhi[Kb][0], acc0, 0,0,0);
        acc0 = __builtin_amdgcn_mfma_f32_32x32x16_bf16(ah, Blo[Kb][0], acc0, 0,0,0);
        acc0 = __builtin_amdgcn_mfma_f32_32x32x16_bf16(al, Bhi[Kb][0], acc0, 0,0,0);
        acc1 = __builtin_amdgcn_mfma_f32_32x32x16_bf16(ah, Bhi[Kb][1], acc1, 0,0,0);
        acc1 = __builtin_amdgcn_mfma_f32_32x32x16_bf16(ah, Blo[Kb][1], acc1, 0,0,0);
        acc1 = __builtin_amdgcn_mfma_f32_32x32x16_bf16(al, Bhi[Kb][1], acc1, 0,0,0);
      }
      float b0 = btil[(size_t)t*KK + n];
      float b1 = btil[(size_t)t*KK + 32 + n];
      float mx = 0.f;
#pragma unroll
      for (int i = 0; i < 16; i++){
        acc0[i] *= b0; acc1[i] *= b1;
        mx = fmaxf(mx, fmaxf(acc0[i], acc1[i]));
      }
      mx = wred_max(mx);
      if (lane == 0) wmax[s&1][w] = mx;
      __syncthreads();
      float inv = 1.f/fmaxf(wmax[s&1][0], wmax[s&1][1]);
#pragma unroll
      for (int r = 0; r < 16; r++){
        int row = w*32 + (r&3) + 8*(r>>2) + 4*(lane>>5);
        G[row*GP + n]      = acc0[r]*inv;
        G[row*GP + 32 + n] = acc1[r]*inv;
      }
      __syncthreads();
    }
  }
  float* dst = H32 + (size_t)chunk*4096;
  for (int v = tid; v < 4096; v += 128) dst[v] = G[(v>>6)*GP + (v&63)];
  float* dstT = H32T + (size_t)chunk*4096;
  for (int v = tid; v < 4096; v += 128) dstT[v] = G[(v&63)*GP + (v>>6)];
}

// ---------------- chain-combine body ----------------
__device__ void chain_body(const float* __restrict__ s0, int chain,
    float* __restrict__ X, float (*wmax)[2],
    float* __restrict__ dstLin, int tid, int w, int lane)
{
  int kb8 = (lane >> 5)*8;
  int n = lane & 31;
  int m = w*32 + n;

  for (int v = tid; v < 4096; v += 128) X[(v>>6)*GP + (v&63)] = s0[v];
  __syncthreads();

  for (int j = 1; j < chain; j++){
    const float* Y = s0 + (size_t)j*4096;
    bf16x8 Bh[4][2], Bl[4][2];
#pragma unroll
    for (int Kb = 0; Kb < 4; Kb++)
#pragma unroll
      for (int J = 0; J < 2; J++){
#pragma unroll
        for (int jj = 0; jj < 8; jj++){
          float p = Y[(Kb*16 + kb8 + jj)*64 + J*32 + n];
          __bf16 h = (__bf16)p;
          Bh[Kb][J][jj] = h;
          Bl[Kb][J][jj] = (__bf16)(p - (float)h);
        }
      }
    f32x16 acc0, acc1;
#pragma unroll
    for (int i = 0; i < 16; i++){ acc0[i] = 0.f; acc1[i] = 0.f; }
#pragma unroll
    for (int Kb = 0; Kb < 4; Kb++){
      float4 x0 = *(const float4*)&X[m*GP + Kb*16 + kb8];
      float4 x1 = *(const float4*)&X[m*GP + Kb*16 + kb8 + 4];
      float xv[8] = {x0.x,x0.y,x0.z,x0.w,x1.x,x1.y,x1.z,x1.w};
      bf16x8 ah, al;
#pragma unroll
      for (int q = 0; q < 8; q++){
        __bf16 h = (__bf16)xv[q];
        ah[q] = h;
        al[q] = (__bf16)(xv[q] - (float)h);
      }
      acc0 = __builtin_amdgcn_mfma_f32_32x32x16_bf16(ah, Bh[Kb][0], acc0, 0,0,0);
      acc0 = __builtin_amdgcn_mfma_f32_32x32x16_bf16(ah, Bl[Kb][0], acc0, 0,0,0);
      acc0 = __builtin_amdgcn_mfma_f32_32x32x16_bf16(al, Bh[Kb][0], acc0, 0,0,0);
      acc1 = __builtin_amdgcn_mfma_f32_32x32x16_bf16(ah, Bh[Kb][1], acc1, 0,0,0);
      acc1 = __builtin_amdgcn_mfma_f32_32x32x16_bf16(ah, Bl[Kb][1], acc1, 0,0,0);
      acc1 = __builtin_amdgcn_mfma_f32_32x32x16_bf16(al, Bh[Kb][1], acc1, 0,0,0);
    }
    float mx = 0.f;
#pragma unroll
    for (int i = 0; i < 16; i++) mx = fmaxf(mx, fmaxf(acc0[i], acc1[i]));
    mx = wred_max(mx);
    if (lane == 0) wmax[j&1][w] = mx;
    __syncthreads();
    float inv = 1.f/fmaxf(wmax[j&1][0], wmax[j&1][1]);
#pragma unroll
    for (int r = 0; r < 16; r++){
      int row = w*32 + (r&3) + 8*(r>>2) + 4*(lane>>5);
      X[row*GP + n]      = acc0[r]*inv;
      X[row*GP + 32 + n] = acc1[r]*inv;
    }
    __syncthreads();
  }
  for (int v = tid; v < 4096; v += 128) dstLin[v] = X[(v>>6)*GP + (v&63)];
}

// ---------------- super: S[j] = H32[16j]...H32[16j+15] (+ transpose) ----------------
__global__ void __launch_bounds__(128, 1) k_super(const float* __restrict__ H32,
        float* __restrict__ S, float* __restrict__ ST)
{
  __shared__ float X[64*GP];
  __shared__ float wmax[2][2];
  int tid = threadIdx.x, w = tid >> 6, lane = tid & 63;
  int j = blockIdx.x;
  chain_body(H32 + (size_t)j*16*4096, 16, X, wmax, S + (size_t)j*4096, tid, w, lane);
  __syncthreads();
  float* dstT = ST + (size_t)j*4096;
  for (int v = tid; v < 4096; v += 128) dstT[v] = X[(v&63)*GP + (v>>6)];
}

#define P2_LOAD(H, base, cc) do { const float* g_ = (base) + (size_t)(cc)*4096; \
  _Pragma("unroll") for (int i_ = 0; i_ < 64; i_++) H[i_] = g_[i_*64 + lane]; } while(0)
#define P2_STEP_NN(H, v) do { float p0_=0.f,p1_=0.f,p2_=0.f,p3_=0.f; \
  _Pragma("unroll") for (int i_ = 0; i_ < 16; i_++){ \
    p0_ = fmaf(__shfl(v, i_,      64), H[i_],      p0_); \
    p1_ = fmaf(__shfl(v, i_ + 16, 64), H[i_ + 16], p1_); \
    p2_ = fmaf(__shfl(v, i_ + 32, 64), H[i_ + 32], p2_); \
    p3_ = fmaf(__shfl(v, i_ + 48, 64), H[i_ + 48], p3_); } \
  v = (p0_ + p1_) + (p2_ + p3_); } while(0)

// ---------------- pass3': per-block boundary matvecs + 64-step chunk recurrences ----------------
__global__ void __launch_bounds__(64, 1) k_pass3p(const float* __restrict__ Pm, const float* __restrict__ PTm,
   const float* __restrict__ H32, const float* __restrict__ H32T,
   const float* __restrict__ Sup, const float* __restrict__ SupT,
   const float* __restrict__ logB, const float* __restrict__ mrow, const float* __restrict__ btil,
   const float* __restrict__ log_pi,
   float* __restrict__ alphahat, float* __restrict__ betahat, float* __restrict__ llpart)
{
  int lane = threadIdx.x;
  int bid = blockIdx.x;
  float Hr[64];
  if (bid < 128){
    int c = bid;
    float Preg[64];
#pragma unroll
    for (int i = 0; i < 64; i++) Preg[i] = Pm[i*64 + lane];
    float a; float llacc = 0.f;
    int tstart;
    float x0v = log_pi[lane] + logB[lane];
    float mm0 = wred_max(x0v);
    float e0 = expf(x0v - mm0);
    float ss0 = wred_sum(e0);
    if (c == 0){
      a = e0/ss0;
      llacc = mm0 + logf(ss0);
      alphahat[lane] = a;
      tstart = 1;
    } else {
      // boundary: alpha after step 64c-1 = a0 * H32[0..2c-1], via supers of 16
      float v = e0/ss0;
      int q = (2*c) >> 4;
      for (int jj = 0; jj < q; jj++){
        P2_LOAD(Hr, Sup, jj);
        P2_STEP_NN(Hr, v);
        v /= wred_sum(v);
      }
      for (int jj = 16*q; jj < 2*c; jj++){
        P2_LOAD(Hr, H32, jj);
        P2_STEP_NN(Hr, v);
        v /= wred_sum(v);
      }
      a = v;
      tstart = c*64;
    }
    int tend = c*64 + 64;
    float bt = btil[(size_t)tstart*KK + lane];
    for (int t = tstart; t < tend; t++){
      float btn = 0.f;
      if (t + 1 < tend) btn = btil[(size_t)(t+1)*KK + lane];
      float mr = mrow[t];
      float p0 = 0.f, p1 = 0.f, p2 = 0.f, p3 = 0.f;
#pragma unroll
      for (int i = 0; i < 16; i++){
        p0 = fmaf(__shfl(a, i,      64), Preg[i],      p0);
        p1 = fmaf(__shfl(a, i + 16, 64), Preg[i + 16], p1);
        p2 = fmaf(__shfl(a, i + 32, 64), Preg[i + 32], p2);
        p3 = fmaf(__shfl(a, i + 48, 64), Preg[i + 48], p3);
      }
      float pred = (p0 + p1) + (p2 + p3);
      a = pred * bt;
      if (((t - tstart) & 3) == 3 || t == tend - 1){
        float s = wred_sum(a);
        a = a / s;
        llacc += logf(s);
      }
      llacc += mr;
      alphahat[(size_t)t*KK + lane] = a;
      bt = btn;
    }
    if (lane == 0) llpart[c] = llacc;
  } else {
    int c = bid - 128;
    float PTreg[64];
#pragma unroll
    for (int j = 0; j < 64; j++) PTreg[j] = PTm[j*64 + lane];
    float b, lb;
    if (c == 127){
      b = 1.f; lb = 0.f;
    } else {
      // boundary: beta at step 64c+63 = H32[2c+2..255] * 1, applied right-to-left via transposes
      float v = 1.f;
      int start = 2*c + 2;
      int m0 = (start + 15) >> 4;
      for (int jj = 15; jj >= m0; jj--){
        P2_LOAD(Hr, SupT, jj);
        P2_STEP_NN(Hr, v);
        v /= wred_max(v);
      }
      for (int jj = 16*m0 - 1; jj >= start; jj--){
        P2_LOAD(Hr, H32T, jj);
        P2_STEP_NN(Hr, v);
        v /= wred_max(v);
      }
      b = v;
      lb = logf(b);
    }
    int t1 = c*64 + 63;
    betahat[(size_t)t1*KK + lane] = b;
    float lgb = logB[(size_t)t1*KK + lane];
    float mrn = mrow[t1];
    for (int t = t1 - 1; t >= c*64; t--){
      float lgbn = 0.f, mrnn = 0.f;
      if (t > c*64){
        lgbn = logB[(size_t)t*KK + lane];
        mrnn = mrow[t];
      }
      float lv = (lgb - mrn) + lb;
      float vm = wred_max(lv);
      float vv = expf(lv - vm);
      float q0 = 0.f, q1r = 0.f, q2 = 0.f, q3 = 0.f;
#pragma unroll
      for (int j = 0; j < 16; j++){
        q0  = fmaf(PTreg[j],      __shfl(vv, j,      64), q0);
        q1r = fmaf(PTreg[j + 16], __shfl(vv, j + 16, 64), q1r);
        q2  = fmaf(PTreg[j + 32], __shfl(vv, j + 32, 64), q2);
        q3  = fmaf(PTreg[j + 48], __shfl(vv, j + 48, 64), q3);
      }
      b = (q0 + q1r) + (q2 + q3);   // vm-shift keeps b bounded; no renorm needed
      lb = logf(b);
      betahat[(size_t)t*KK + lane] = b;
      lgb = lgbn; mrn = mrnn;
    }
  }
}

// ---------------- merged outputs: rhat + xihat + ll ----------------
__global__ void __launch_bounds__(256) k_outs(const float* __restrict__ ah,
     const float* __restrict__ bh, const float* __restrict__ ElogA,
     const float* __restrict__ logB, const float* __restrict__ llp,
     float* __restrict__ out_rhat, float* __restrict__ out_xi, float* __restrict__ out_ll)
{
  __shared__ float la[64], wc[64];
  __shared__ float redm[4], reds[4];
  int tid = threadIdx.x;
  int b = blockIdx.x;
  if (tid < 64) la[tid] = logf(ah[(size_t)b*KK + tid]);
  else if (tid < 128 && b < T_LEN-1){
    int j = tid - 64;
    wc[j] = logB[(size_t)(b+1)*KK + j] + logf(bh[(size_t)(b+1)*KK + j]);
  }
  __syncthreads();
  if (tid < 64){
    float s = la[tid] + logf(bh[(size_t)b*KK + tid]);
    float m = wred_max(s);
    float p = (m < -3.0e37f) ? 1.f : expf(s - m);
    float ss = wred_sum(p);
    out_rhat[(size_t)b*KK + tid] = p/ss;
  }
  if (b == T_LEN-1){
    if (tid >= 64 && tid < 128){
      int i = tid - 64;
      float v = llp[i] + llp[i + 64];
      v = wred_sum(v);
      if (i == 0) out_ll[0] = v;
    }
    return;
  }
  int lane = tid & 63, w = tid >> 6;
  int j0 = (lane & 15) << 2;
  int ibase = w*16 + (lane >> 4)*4;
  float4 wc4 = *(float4*)&wc[j0];
  float sv[16];
  float mx = -3.0e38f;
#pragma unroll
  for (int ii = 0; ii < 4; ii++){
    float lai = la[ibase + ii];
    float4 e4 = *(const float4*)&ElogA[(ibase+ii)*KK + j0];
    float s0 = lai + e4.x + wc4.x;
    float s1 = lai + e4.y + wc4.y;
    float s2 = lai + e4.z + wc4.z;
    float s3 = lai + e4.w + wc4.w;
    sv[ii*4+0]=s0; sv[ii*4+1]=s1; sv[ii*4+2]=s2; sv[ii*4+3]=s3;
    mx = fmaxf(fmaxf(fmaxf(mx, s0), fmaxf(s1, s2)), s3);
  }
  float mxw = wred_max(mx);
  if (lane == 0) redm[w] = mxw;
  __syncthreads();
  float m = fmaxf(fmaxf(redm[0], redm[1]), fmaxf(redm[2], redm[3]));
  bool degen = !(m > -3.0e37f);
  float pv[16]; float ps = 0.f;
#pragma unroll
  for (int n = 0; n < 16; n++){
    float p = degen ? 1.f : expf(sv[n] - m);
    pv[n] = p; ps += p;
  }
  float psw = wred_sum(ps);
  if (lane == 0) reds[w] = psw;
  __syncthreads();
  float inv = 1.f/(reds[0] + reds[1] + reds[2] + reds[3]);
  float* dst = out_xi + (size_t)b*4096;
#pragma unroll
  for (int ii = 0; ii < 4; ii++){
    float4 o;
    o.x = pv[ii*4+0]*inv; o.y = pv[ii*4+1]*inv;
    o.z = pv[ii*4+2]*inv; o.w = pv[ii*4+3]*inv;
    *(float4*)&dst[(ibase+ii)*KK + j0] = o;
  }
}

extern "C" void kernel_launch(void* const* d_in, const int* in_sizes, int n_in,
                              void* d_out, int out_size, void* d_ws, size_t ws_size,
                              hipStream_t stream)
{
  const float* mu    = (const float*)d_in[0];
  const float* dvar  = (const float*)d_in[1];
  const float* niwmu = (const float*)d_in[2];
  const float* Psi   = (const float*)d_in[3];
  const float* nu    = (const float*)d_in[4];
  const float* phi   = (const float*)d_in[5];
  const float* lpi   = (const float*)d_in[6];
  float* out = (float*)d_out;
  float* ws  = (float*)d_ws;

  size_t o = 0;
  float* EbfF   = ws + o; o += (size_t)DD*DD*KK/2;
  float* EdiagT = ws + o; o += (size_t)DD*KK;
  float* cvecT  = ws + o; o += (size_t)DD*KK;
  float* rK     = ws + o; o += KK;
  float* Lhalf  = ws + o; o += KK;
  float* sclK   = ws + o; o += KK;
  float* ElogA  = ws + o; o += KK*KK;
  float* P      = ws + o; o += KK*KK;
  float* PT     = ws + o; o += KK*KK;
  float* logB   = ws + o; o += (size_t)T_LEN*KK;
  float* mrowp  = ws + o; o += T_LEN;
  float* btil   = ws + o; o += (size_t)T_LEN*KK;
  float* part   = ws + o; o += (size_t)4*T_LEN*KK;
  float* H32    = ws + o; o += (size_t)256*4096;
  float* H32T   = ws + o; o += (size_t)256*4096;
  float* Sup    = ws + o; o += (size_t)16*4096;
  float* SupT   = ws + o; o += (size_t)16*4096;
  float* llp    = ws + o; o += 128;
  float* ah     = ws + o; o += (size_t)T_LEN*KK;
  float* bh     = ws + o; o += (size_t)T_LEN*KK;
  if (ws_size < o*sizeof(float)) return;

  __bf16* Ebf = (__bf16*)EbfF;

  hipFuncSetAttribute((const void*)k_neumann, hipFuncAttributeMaxDynamicSharedMemorySize, 2*DD*RS*4);

  k_neumann<<<64, 256, 2*DD*RS*4, stream>>>(Psi, niwmu, nu, phi, Ebf, EdiagT, cvecT, rK, Lhalf, sclK, ElogA, P, PT);
  k_q1<<<256, 256, 0, stream>>>(mu, Ebf, part);
  k_logBall<<<256, 256, 0, stream>>>(part, mu, dvar, cvecT, EdiagT, rK, Lhalf, sclK, logB, mrowp, btil);
  k_pass32<<<256, 128, 0, stream>>>(P, btil, H32, H32T);
  k_super<<<16, 128, 0, stream>>>(H32, Sup, SupT);
  k_pass3p<<<256, 64, 0, stream>>>(P, PT, H32, H32T, Sup, SupT, logB, mrowp, btil, lpi, ah, bh, llp);
  k_outs<<<T_LEN, 256, 0, stream>>>(ah, bh, ElogA, logB, llp, out, out + (size_t)T_LEN*KK,
                                    out + (size_t)T_LEN*KK + (size_t)(T_LEN-1)*KK*KK);
}